// Round 16
// baseline (289.171 us; speedup 1.0000x reference)
//
#include <hip/hip_runtime.h>

#define EPSV 1e-5f

typedef __bf16 bf16x8 __attribute__((ext_vector_type(8)));
typedef float f32x4 __attribute__((ext_vector_type(4)));
typedef float f32x2 __attribute__((ext_vector_type(2)));
typedef unsigned int u32x4 __attribute__((ext_vector_type(4)));
typedef unsigned short u16x4 __attribute__((ext_vector_type(4)));

__device__ __forceinline__ unsigned short f2bf(float f) {
  return __builtin_bit_cast(unsigned short, static_cast<__bf16>(f));
}

constexpr int Himg = 112, Wimg = 112, HWp = Himg * Wimg;  // 12544

// ---------------------------------------------------------------------------
// prep_misc: pack weights into per-lane MFMA A-fragment order + BN scale/shift
//   for all three BNs. prm: [0)=s1 [64)=h1 [128)=s2 [192)=h2 [256)=s0 [320)=h0
// ---------------------------------------------------------------------------
__global__ __launch_bounds__(256) void prep_misc(
    const float* __restrict__ w1, const float* __restrict__ w2,
    const float* __restrict__ g0, const float* __restrict__ b0,
    const float* __restrict__ m0, const float* __restrict__ v0,
    const float* __restrict__ g1, const float* __restrict__ b1,
    const float* __restrict__ m1, const float* __restrict__ v1,
    const float* __restrict__ g2, const float* __restrict__ b2,
    const float* __restrict__ m2, const float* __restrict__ v2,
    unsigned short* __restrict__ wt1, unsigned short* __restrict__ wt2,
    float* __restrict__ prm)
{
  int id = blockIdx.x * 256 + threadIdx.x;
  for (int i = id; i < 9 * 2 * 4 * 512; i += gridDim.x * 256) {
    int j   = i & 7;
    int l   = (i >> 3) & 63;
    int c   = (i >> 9) & 3;
    int ks  = (i >> 11) & 1;
    int tap = i >> 12;
    int co  = c * 16 + (l & 15);
    int ci  = ks * 32 + (l >> 4) * 8 + j;
    int kh  = tap / 3, kw = tap - kh * 3;
    int src = ((co * 64 + ci) * 3 + kh) * 3 + kw;
    wt1[i] = f2bf(w1[src]);
    wt2[i] = f2bf(w2[src]);
  }
  if (id < 64) {
    float s1 = g1[id] * rsqrtf(v1[id] + EPSV);
    prm[id]      = s1;
    prm[64 + id] = b1[id] - m1[id] * s1;
    float s2 = g2[id] * rsqrtf(v2[id] + EPSV);
    prm[128 + id] = s2;
    prm[192 + id] = b2[id] - m2[id] * s2;
    float s0 = g0[id] * rsqrtf(v0[id] + EPSV);
    prm[256 + id] = s0;
    prm[320 + id] = b0[id] - m0[id] * s0;
  }
}

// ---------------------------------------------------------------------------
// conv1k: persistent conv1 with fused BN0 staging, CONFLICT-FREE layout.
//   Staging thread map (wp=t>>3, k=t&7): thread owns pixels {2wp, 2wp+1} x
//   channels [8k, 8k+8). Per row: 8 x f32x2 loads (64B-coalesced per plane),
//   BN0 in regs, pack -> 2 x ds_write_b128 at P*128+((k^(P&7))<<4) — the
//   address family measured at 0 conflicts since R6. (R14/R15's cs/wb scalar
//   u32 emit put 16 lanes on 2 banks: 7.7M conflict cycles/dispatch.)
//   Prefetch 1 row/tile into regs (16 VGPR); rows 2-4 loaded at restage.
// ---------------------------------------------------------------------------
__global__ __launch_bounds__(448, 2) void conv1k(
    const float* __restrict__ xsrc,
    const unsigned short* __restrict__ wP,
    const float* __restrict__ scale, const float* __restrict__ shift,
    const float* __restrict__ aP,
    const float* __restrict__ bn0sc, const float* __restrict__ bn0sh,
    unsigned short* __restrict__ dstb)
{
  constexpr int RS   = 114 * 128;   // 14592
  constexpr int WOFF = 6 * RS;      // 87552
  __shared__ __align__(16) unsigned char lds[WOFF + 73728];  // 161280

  const int t = threadIdx.x;
  const int b = blockIdx.x;
  const int n = b >> 2, q = b & 3;
  const int qbase = q * 28;
  const size_t ibase = (size_t)n * HWp;
  const float* xn = xsrc + (size_t)n * 64 * HWp;

  const int wv = t >> 6, l = t & 63;
  const int lo = l & 15, grp = l >> 4;

  // staging map + per-thread BN0 constants (channels 8k..8k+7)
  const int wp = t >> 3, kS = t & 7;
  float sc8[8], sh8[8];
#pragma unroll
  for (int m = 0; m < 8; ++m) {
    sc8[m] = bn0sc[kS * 8 + m];
    sh8[m] = bn0sh[kS * 8 + m];
  }

  auto load_row = [&](int hh, f32x2 (&v)[8]) -> bool {
    bool valid = (unsigned)hh < 112u;
#pragma unroll
    for (int m = 0; m < 8; ++m) {
      f32x2 z = {0.f, 0.f};
      v[m] = valid
           ? *reinterpret_cast<const f32x2*>(xn + (size_t)(kS * 8 + m) * HWp + hh * Wimg + wp * 2)
           : z;
    }
    return valid;
  };
  auto emit_row = [&](int rbX, const f32x2 (&v)[8], bool valid) {
#pragma unroll
    for (int d = 0; d < 2; ++d) {
      u32x4 pk;
#pragma unroll
      for (int dd = 0; dd < 4; ++dd) {
        float flo = valid ? v[2 * dd][d] * sc8[2 * dd] + sh8[2 * dd] : 0.f;
        float fhi = valid ? v[2 * dd + 1][d] * sc8[2 * dd + 1] + sh8[2 * dd + 1] : 0.f;
        pk[dd] = (unsigned int)f2bf(flo) | ((unsigned int)f2bf(fhi) << 16);
      }
      int P = wp * 2 + d + 1;
      *reinterpret_cast<u32x4*>(&lds[rbX + P * 128 + ((kS ^ (P & 7)) << 4)]) = pk;
    }
  };

  // weights full (once)
#pragma unroll
  for (int it = 0; it < 11; ++it) {
    int idx = t + it * 448;
    if (it < 10 || idx < 4608) {
      u32x4 v = *reinterpret_cast<const u32x4*>(wP + idx * 8);
      *reinterpret_cast<u32x4*>(&lds[WOFF + idx * 16]) = v;
    }
  }
  // halo zero: wpad cols (P=0,113), 6 slots
  if (t < 96) {
    int r = t >> 4, P = ((t >> 3) & 1) ? 113 : 0, k = t & 7;
    u32x4 z = {0u, 0u, 0u, 0u};
    *reinterpret_cast<u32x4*>(&lds[r * RS + P * 128 + ((k ^ (P & 7)) << 4)]) = z;
  }
  // rows qbase-1 .. qbase+4 -> slots 0..5
#pragma unroll
  for (int r = 0; r < 6; ++r) {
    f32x2 A[8];
    bool v = load_row(qbase - 1 + r, A);
    emit_row(r * RS, A, v);
  }
  __syncthreads();

  int rb0 = 0 * RS, rb1 = 1 * RS, rb2 = 2 * RS, rb3 = 3 * RS, rb4 = 4 * RS, rb5 = 5 * RS;

  for (int T = 0; T < 7; ++T) {
    const int r0 = qbase + T * 4;

    // prefetch next tile's first row into regs
    f32x2 pA[8];
    bool pvA = false;
    if (T < 6) pvA = load_row(r0 + 5, pA);

    f32x4 acc[4][4];
#pragma unroll
    for (int c = 0; c < 4; ++c)
#pragma unroll
      for (int p = 0; p < 4; ++p) {
        f32x4 z = {0.f, 0.f, 0.f, 0.f};
        acc[c][p] = z;
      }

#pragma unroll
    for (int s = 0; s < 18; ++s) {
      const int tap = s >> 1, ks = s & 1;
      const int dh = tap / 3, dw = tap - dh * 3;
      bf16x8 wf[4], pf[4];
#pragma unroll
      for (int c = 0; c < 4; ++c)
        wf[c] = *reinterpret_cast<const bf16x8*>(&lds[WOFF + (s * 4 + c) * 1024 + l * 16]);
      const int Pr = wv * 16 + lo + dw;
      const int c8 = (ks << 2) | grp;
      const int pbyte = Pr * 128 + ((c8 ^ (Pr & 7)) << 4);
#pragma unroll
      for (int p = 0; p < 4; ++p) {
        const int rr = p + dh;
        const int rbr = (rr == 0) ? rb0 : (rr == 1) ? rb1 : (rr == 2) ? rb2
                      : (rr == 3) ? rb3 : (rr == 4) ? rb4 : rb5;
        pf[p] = *reinterpret_cast<const bf16x8*>(&lds[rbr + pbyte]);
      }
#pragma unroll
      for (int c = 0; c < 4; ++c)
#pragma unroll
        for (int p = 0; p < 4; ++p)
          acc[c][p] = __builtin_amdgcn_mfma_f32_16x16x32_bf16(wf[c], pf[p], acc[c][p], 0, 0, 0);
    }

#pragma unroll
    for (int c = 0; c < 4; ++c) {
      const int co0 = c * 16 + grp * 4;
      float s_[4], h_[4], a_[4];
#pragma unroll
      for (int j = 0; j < 4; ++j) {
        s_[j] = scale[co0 + j];
        h_[j] = shift[co0 + j];
        a_[j] = aP[co0 + j];
      }
      const int w = wv * 16 + lo;
#pragma unroll
      for (int p = 0; p < 4; ++p) {
        const int hh = r0 + p;
        f32x4 v = acc[c][p];
        u16x4 u;
#pragma unroll
        for (int j = 0; j < 4; ++j) {
          float vv = v[j] * s_[j] + h_[j];
          vv = vv >= 0.f ? vv : vv * a_[j];
          u[j] = f2bf(vv);
        }
        *reinterpret_cast<u16x4*>(dstb + (ibase + hh * Wimg + w) * 64 + co0) = u;
      }
    }

    if (T < 6) {
      __syncthreads();
      emit_row(rb0, pA, pvA);
#pragma unroll
      for (int rr = 1; rr < 4; ++rr) {
        f32x2 tA[8];
        bool v = load_row(r0 + 5 + rr, tA);
        emit_row((rr == 1) ? rb1 : (rr == 2) ? rb2 : rb3, tA, v);
      }
      __syncthreads();
    }

    int n0 = rb4, n1 = rb5, n2 = rb0, n3 = rb1, n4 = rb2, n5 = rb3;
    rb0 = n0; rb1 = n1; rb2 = n2; rb3 = n3; rb4 = n4; rb5 = n5;
  }
}

// ---------------------------------------------------------------------------
// conv2k: 2-row-tile conv2 (R15, unchanged). 14 tiles of 2 rows x 112 x 64co;
//   ring 4 slots + full weights (132096 B LDS); half-resid prefetch (16 f32)
//   hides under the K-loop.
// ---------------------------------------------------------------------------
__global__ __launch_bounds__(448, 2) void conv2k(
    const unsigned short* __restrict__ src,   // y1 bf16 NHWC
    const unsigned short* __restrict__ wP,
    const float* __restrict__ scale, const float* __restrict__ shift,
    const float* __restrict__ aP,
    float* __restrict__ dstf,
    const float* __restrict__ resid)
{
  constexpr int RS   = 114 * 128;   // 14592
  constexpr int WOFF = 4 * RS;      // 58368
  __shared__ __align__(16) unsigned char lds[WOFF + 73728];  // 132096

  const int t = threadIdx.x;
  const int b = blockIdx.x;
  const int n = b >> 2, q = b & 3;
  const int qbase = q * 28;
  const size_t ibase = (size_t)n * HWp;

  const int wv = t >> 6, l = t & 63;
  const int lo = l & 15, grp = l >> 4;

#pragma unroll
  for (int it = 0; it < 11; ++it) {
    int idx = t + it * 448;
    if (it < 10 || idx < 4608) {
      u32x4 v = *reinterpret_cast<const u32x4*>(wP + idx * 8);
      *reinterpret_cast<u32x4*>(&lds[WOFF + idx * 16]) = v;
    }
  }
  if (t < 64) {
    int r = t >> 4, P = ((t >> 3) & 1) ? 113 : 0, k = t & 7;
    u32x4 z = {0u, 0u, 0u, 0u};
    *reinterpret_cast<u32x4*>(&lds[r * RS + P * 128 + ((k ^ (P & 7)) << 4)]) = z;
  }
#pragma unroll
  for (int it = 0; it < 8; ++it) {
    int r = it >> 1;
    int rem = t + (it & 1) * 448;
    int w = rem >> 3, k = rem & 7;
    int hh = qbase - 1 + r;
    u32x4 val = {0u, 0u, 0u, 0u};
    if ((unsigned)hh < 112u)
      val = *reinterpret_cast<const u32x4*>(src + (ibase + hh * Wimg + w) * 64 + k * 8);
    int P = w + 1;
    *reinterpret_cast<u32x4*>(&lds[r * RS + P * 128 + ((k ^ (P & 7)) << 4)]) = val;
  }
  __syncthreads();

  int rb0 = 0 * RS, rb1 = 1 * RS, rb2 = 2 * RS, rb3 = 3 * RS;

  for (int T = 0; T < 14; ++T) {
    const int r0 = qbase + T * 2;

    float rres[2][2][4];
#pragma unroll
    for (int c = 0; c < 2; ++c)
#pragma unroll
      for (int p = 0; p < 2; ++p)
#pragma unroll
        for (int j = 0; j < 4; ++j) {
          size_t idx = ((size_t)(n * 64 + c * 16 + grp * 4 + j) * Himg + (r0 + p)) * Wimg
                       + wv * 16 + lo;
          rres[c][p][j] = resid[idx];
        }

    u32x4 preg[4];
    if (T < 13) {
#pragma unroll
      for (int it = 0; it < 4; ++it) {
        int j = it >> 1;
        int rem = t + (it & 1) * 448;
        int w = rem >> 3, k = rem & 7;
        int hh = r0 + 3 + j;
        u32x4 val = {0u, 0u, 0u, 0u};
        if (hh < 112)
          val = *reinterpret_cast<const u32x4*>(src + (ibase + hh * Wimg + w) * 64 + k * 8);
        preg[it] = val;
      }
    }
    __builtin_amdgcn_sched_barrier(0);

    f32x4 acc[4][2];
#pragma unroll
    for (int c = 0; c < 4; ++c)
#pragma unroll
      for (int p = 0; p < 2; ++p) {
        f32x4 z = {0.f, 0.f, 0.f, 0.f};
        acc[c][p] = z;
      }

#pragma unroll
    for (int s = 0; s < 18; ++s) {
      const int tap = s >> 1, ks = s & 1;
      const int dh = tap / 3, dw = tap - dh * 3;
      bf16x8 wf[4], pf[2];
#pragma unroll
      for (int c = 0; c < 4; ++c)
        wf[c] = *reinterpret_cast<const bf16x8*>(&lds[WOFF + (s * 4 + c) * 1024 + l * 16]);
      const int Pr = wv * 16 + lo + dw;
      const int c8 = (ks << 2) | grp;
      const int pbyte = Pr * 128 + ((c8 ^ (Pr & 7)) << 4);
#pragma unroll
      for (int p = 0; p < 2; ++p) {
        const int rr = p + dh;
        const int rbr = (rr == 0) ? rb0 : (rr == 1) ? rb1 : (rr == 2) ? rb2 : rb3;
        pf[p] = *reinterpret_cast<const bf16x8*>(&lds[rbr + pbyte]);
      }
#pragma unroll
      for (int c = 0; c < 4; ++c)
#pragma unroll
        for (int p = 0; p < 2; ++p)
          acc[c][p] = __builtin_amdgcn_mfma_f32_16x16x32_bf16(wf[c], pf[p], acc[c][p], 0, 0, 0);
    }

#pragma unroll
    for (int c = 0; c < 4; ++c) {
      const int co0 = c * 16 + grp * 4;
      float s_[4], h_[4], a_[4];
#pragma unroll
      for (int j = 0; j < 4; ++j) {
        s_[j] = scale[co0 + j];
        h_[j] = shift[co0 + j];
        a_[j] = aP[co0 + j];
      }
      const int w = wv * 16 + lo;
#pragma unroll
      for (int p = 0; p < 2; ++p) {
        const int hh = r0 + p;
        f32x4 v = acc[c][p];
#pragma unroll
        for (int j = 0; j < 4; ++j) {
          size_t idx = ((size_t)(n * 64 + co0 + j) * Himg + hh) * Wimg + w;
          float res = (c < 2) ? rres[c & 1][p][j] : resid[idx];
          float vv = v[j] * s_[j] + h_[j] + res;
          vv = vv >= 0.f ? vv : vv * a_[j];
          dstf[idx] = vv;
        }
      }
    }

    if (T < 13) {
      __syncthreads();
#pragma unroll
      for (int it = 0; it < 4; ++it) {
        int j = it >> 1;
        int rem = t + (it & 1) * 448;
        int w = rem >> 3, k = rem & 7;
        int P = w + 1;
        const int dst = (j == 0) ? rb0 : rb1;
        *reinterpret_cast<u32x4*>(&lds[dst + P * 128 + ((k ^ (P & 7)) << 4)]) = preg[it];
      }
      __syncthreads();
    }

    int n0 = rb2, n1 = rb3, n2 = rb0, n3 = rb1;
    rb0 = n0; rb1 = n1; rb2 = n2; rb3 = n3;
  }
}

// ---------------------------------------------------------------------------
// scratch map:
//   d_ws [0 .. 102,760,448)     : y1 bf16 NHWC
//   d_ws [+0 .. +73,728)        : wt1 packed bf16
//   d_ws [+73,728 .. +147,456)  : wt2 packed bf16
//   d_ws [+147,456 .. +149,000) : prm f32 (384 floats)
// ---------------------------------------------------------------------------
extern "C" void kernel_launch(void* const* d_in, const int* in_sizes, int n_in,
                              void* d_out, int out_size, void* d_ws, size_t ws_size,
                              hipStream_t stream)
{
  const float* x  = (const float*)d_in[0];
  const float* w1 = (const float*)d_in[1];
  const float* w2 = (const float*)d_in[2];
  const float* g0 = (const float*)d_in[3];
  const float* b0 = (const float*)d_in[4];
  const float* m0 = (const float*)d_in[5];
  const float* v0 = (const float*)d_in[6];
  const float* g1 = (const float*)d_in[7];
  const float* b1 = (const float*)d_in[8];
  const float* m1 = (const float*)d_in[9];
  const float* v1 = (const float*)d_in[10];
  const float* g2 = (const float*)d_in[11];
  const float* b2 = (const float*)d_in[12];
  const float* m2 = (const float*)d_in[13];
  const float* v2 = (const float*)d_in[14];
  const float* a1 = (const float*)d_in[15];
  const float* a2 = (const float*)d_in[16];

  unsigned char* wsb = (unsigned char*)d_ws;
  unsigned short* y1  = (unsigned short*)wsb;
  unsigned short* wt1 = (unsigned short*)(wsb + 102760448);
  unsigned short* wt2 = (unsigned short*)(wsb + 102760448 + 73728);
  float* prm          = (float*)(wsb + 102760448 + 2 * 73728);

  prep_misc<<<16, 256, 0, stream>>>(w1, w2, g0, b0, m0, v0, g1, b1, m1, v1,
                                    g2, b2, m2, v2, wt1, wt2, prm);
  conv1k<<<256, 448, 0, stream>>>(x, wt1, prm, prm + 64, a1, prm + 256, prm + 320, y1);
  conv2k<<<256, 448, 0, stream>>>(y1, wt2, prm + 128, prm + 192, a2, (float*)d_out, x);
}

// Round 17
// 250.480 us; speedup vs baseline: 1.1545x; 1.1545x over previous
//
#include <hip/hip_runtime.h>

#define EPSV 1e-5f

typedef __bf16 bf16x8 __attribute__((ext_vector_type(8)));
typedef float f32x4 __attribute__((ext_vector_type(4)));
typedef unsigned int u32x4 __attribute__((ext_vector_type(4)));
typedef unsigned short u16x4 __attribute__((ext_vector_type(4)));

__device__ __forceinline__ unsigned short f2bf(float f) {
  return __builtin_bit_cast(unsigned short, static_cast<__bf16>(f));
}

// conv1 patch swizzle: includes P>>2 so the cs/wb scalar-write pattern
// (P = 4wb+C, quarter-wave shares k) spreads over 8 bank-slots (2-way, free)
// while 16-consecutive-P reads stay <=3-way. (R15: k^(P&7) alone -> 2 slots,
// 8-way, 7.7M conflict cycles. R16: conflict-free map broke coalescing.)
__device__ __forceinline__ int swzB(int P, int k) {
  return P * 128 + (((k ^ (P & 7) ^ ((P >> 2) & 7)) & 7) << 4);
}

constexpr int Himg = 112, Wimg = 112, HWp = Himg * Wimg;  // 12544

// ---------------------------------------------------------------------------
// prep_misc: pack weights into per-lane MFMA A-fragment order + BN scale/shift
//   for all three BNs. prm: [0)=s1 [64)=h1 [128)=s2 [192)=h2 [256)=s0 [320)=h0
// ---------------------------------------------------------------------------
__global__ __launch_bounds__(256) void prep_misc(
    const float* __restrict__ w1, const float* __restrict__ w2,
    const float* __restrict__ g0, const float* __restrict__ b0,
    const float* __restrict__ m0, const float* __restrict__ v0,
    const float* __restrict__ g1, const float* __restrict__ b1,
    const float* __restrict__ m1, const float* __restrict__ v1,
    const float* __restrict__ g2, const float* __restrict__ b2,
    const float* __restrict__ m2, const float* __restrict__ v2,
    unsigned short* __restrict__ wt1, unsigned short* __restrict__ wt2,
    float* __restrict__ prm)
{
  int id = blockIdx.x * 256 + threadIdx.x;
  for (int i = id; i < 9 * 2 * 4 * 512; i += gridDim.x * 256) {
    int j   = i & 7;
    int l   = (i >> 3) & 63;
    int c   = (i >> 9) & 3;
    int ks  = (i >> 11) & 1;
    int tap = i >> 12;
    int co  = c * 16 + (l & 15);
    int ci  = ks * 32 + (l >> 4) * 8 + j;
    int kh  = tap / 3, kw = tap - kh * 3;
    int src = ((co * 64 + ci) * 3 + kh) * 3 + kw;
    wt1[i] = f2bf(w1[src]);
    wt2[i] = f2bf(w2[src]);
  }
  if (id < 64) {
    float s1 = g1[id] * rsqrtf(v1[id] + EPSV);
    prm[id]      = s1;
    prm[64 + id] = b1[id] - m1[id] * s1;
    float s2 = g2[id] * rsqrtf(v2[id] + EPSV);
    prm[128 + id] = s2;
    prm[192 + id] = b2[id] - m2[id] * s2;
    float s0 = g0[id] * rsqrtf(v0[id] + EPSV);
    prm[256 + id] = s0;
    prm[320 + id] = b0[id] - m0[id] * s0;
  }
}

// ---------------------------------------------------------------------------
// conv1k: persistent conv1, fused BN0 staging with the R14 COALESCED load map
//   (cs=t/28: 28 lanes read one 448B plane run, f32x4) + the NEW swzB hash
//   on all patch-region LDS accesses (write 2-way, read <=3-way: ~free).
//   4-row tiles; prefetch 2 rows into regs, 2 loaded at restage.
// ---------------------------------------------------------------------------
__global__ __launch_bounds__(448, 2) void conv1k(
    const float* __restrict__ xsrc,
    const unsigned short* __restrict__ wP,
    const float* __restrict__ scale, const float* __restrict__ shift,
    const float* __restrict__ aP,
    const float* __restrict__ bn0sc, const float* __restrict__ bn0sh,
    unsigned short* __restrict__ dstb)
{
  constexpr int RS   = 114 * 128;   // 14592
  constexpr int WOFF = 6 * RS;      // 87552
  __shared__ __align__(16) unsigned char lds[WOFF + 73728];  // 161280

  const int t = threadIdx.x;
  const int b = blockIdx.x;
  const int n = b >> 2, q = b & 3;
  const int qbase = q * 28;
  const size_t ibase = (size_t)n * HWp;
  const float* xn = xsrc + (size_t)n * 64 * HWp;

  const int wv = t >> 6, l = t & 63;
  const int lo = l & 15, grp = l >> 4;

  // staging map (R14): cs = channel-quad owner, wb = pixel-quad within row
  const int cs = t / 28, wb = t - cs * 28;
  const int w0s = wb * 4;
  float scv[4], shv[4];
#pragma unroll
  for (int cc = 0; cc < 4; ++cc) {
    scv[cc] = bn0sc[cs * 4 + cc];
    shv[cc] = bn0sh[cs * 4 + cc];
  }

  auto load_rowx = [&](int hh, f32x4 (&A)[2], f32x4 (&B)[2]) -> bool {
    bool valid = (unsigned)hh < 112u;
#pragma unroll
    for (int u = 0; u < 2; ++u) {
      f32x4 z = {0.f, 0.f, 0.f, 0.f};
      A[u] = z; B[u] = z;
      if (valid) {
        const int ca = cs * 4 + u * 2;
        A[u] = *reinterpret_cast<const f32x4*>(xn + (size_t)ca * HWp + hh * Wimg + w0s);
        B[u] = *reinterpret_cast<const f32x4*>(xn + (size_t)(ca + 1) * HWp + hh * Wimg + w0s);
      }
    }
    return valid;
  };
  auto emit_rowx = [&](int rbX, const f32x4 (&A)[2], const f32x4 (&B)[2], bool valid) {
#pragma unroll
    for (int u = 0; u < 2; ++u) {
      const int ca = cs * 4 + u * 2;
      const int kk = ca >> 3;
      const int off = (ca & 7) * 2;
#pragma unroll
      for (int j = 0; j < 4; ++j) {
        float fa = valid ? A[u][j] * scv[u * 2] + shv[u * 2] : 0.f;
        float fb = valid ? B[u][j] * scv[u * 2 + 1] + shv[u * 2 + 1] : 0.f;
        unsigned int pk = (unsigned int)f2bf(fa) | ((unsigned int)f2bf(fb) << 16);
        int P = w0s + j + 1;
        *reinterpret_cast<unsigned int*>(&lds[rbX + swzB(P, kk) + off]) = pk;
      }
    }
  };

  // weights full (once), linear region — untouched by hash change
#pragma unroll
  for (int it = 0; it < 11; ++it) {
    int idx = t + it * 448;
    if (it < 10 || idx < 4608) {
      u32x4 v = *reinterpret_cast<const u32x4*>(wP + idx * 8);
      *reinterpret_cast<u32x4*>(&lds[WOFF + idx * 16]) = v;
    }
  }
  // halo zero: wpad cols (P=0,113), 6 slots — swzB hash
  if (t < 96) {
    int r = t >> 4, P = ((t >> 3) & 1) ? 113 : 0, k = t & 7;
    u32x4 z = {0u, 0u, 0u, 0u};
    *reinterpret_cast<u32x4*>(&lds[r * RS + swzB(P, k)]) = z;
  }
  // rows qbase-1 .. qbase+4 -> slots 0..5
#pragma unroll
  for (int r = 0; r < 6; ++r) {
    f32x4 A[2], B[2];
    bool v = load_rowx(qbase - 1 + r, A, B);
    emit_rowx(r * RS, A, B, v);
  }
  __syncthreads();

  int rb0 = 0 * RS, rb1 = 1 * RS, rb2 = 2 * RS, rb3 = 3 * RS, rb4 = 4 * RS, rb5 = 5 * RS;

  for (int T = 0; T < 7; ++T) {
    const int r0 = qbase + T * 4;

    f32x4 pA[2][2], pB[2][2];
    bool pv[2];
    if (T < 6) {
#pragma unroll
      for (int rr = 0; rr < 2; ++rr)
        pv[rr] = load_rowx(r0 + 5 + rr, pA[rr], pB[rr]);
    }

    f32x4 acc[4][4];
#pragma unroll
    for (int c = 0; c < 4; ++c)
#pragma unroll
      for (int p = 0; p < 4; ++p) {
        f32x4 z = {0.f, 0.f, 0.f, 0.f};
        acc[c][p] = z;
      }

#pragma unroll
    for (int s = 0; s < 18; ++s) {
      const int tap = s >> 1, ks = s & 1;
      const int dh = tap / 3, dw = tap - dh * 3;
      bf16x8 wf[4], pf[4];
#pragma unroll
      for (int c = 0; c < 4; ++c)
        wf[c] = *reinterpret_cast<const bf16x8*>(&lds[WOFF + (s * 4 + c) * 1024 + l * 16]);
      const int Pr = wv * 16 + lo + dw;
      const int c8 = (ks << 2) | grp;
      const int pbyte = swzB(Pr, c8);
#pragma unroll
      for (int p = 0; p < 4; ++p) {
        const int rr = p + dh;
        const int rbr = (rr == 0) ? rb0 : (rr == 1) ? rb1 : (rr == 2) ? rb2
                      : (rr == 3) ? rb3 : (rr == 4) ? rb4 : rb5;
        pf[p] = *reinterpret_cast<const bf16x8*>(&lds[rbr + pbyte]);
      }
#pragma unroll
      for (int c = 0; c < 4; ++c)
#pragma unroll
        for (int p = 0; p < 4; ++p)
          acc[c][p] = __builtin_amdgcn_mfma_f32_16x16x32_bf16(wf[c], pf[p], acc[c][p], 0, 0, 0);
    }

#pragma unroll
    for (int c = 0; c < 4; ++c) {
      const int co0 = c * 16 + grp * 4;
      float s_[4], h_[4], a_[4];
#pragma unroll
      for (int j = 0; j < 4; ++j) {
        s_[j] = scale[co0 + j];
        h_[j] = shift[co0 + j];
        a_[j] = aP[co0 + j];
      }
      const int w = wv * 16 + lo;
#pragma unroll
      for (int p = 0; p < 4; ++p) {
        const int hh = r0 + p;
        f32x4 v = acc[c][p];
        u16x4 u;
#pragma unroll
        for (int j = 0; j < 4; ++j) {
          float vv = v[j] * s_[j] + h_[j];
          vv = vv >= 0.f ? vv : vv * a_[j];
          u[j] = f2bf(vv);
        }
        *reinterpret_cast<u16x4*>(dstb + (ibase + hh * Wimg + w) * 64 + co0) = u;
      }
    }

    if (T < 6) {
      __syncthreads();
      emit_rowx(rb0, pA[0], pB[0], pv[0]);
      emit_rowx(rb1, pA[1], pB[1], pv[1]);
#pragma unroll
      for (int rr = 2; rr < 4; ++rr) {
        f32x4 tA[2], tB[2];
        bool v = load_rowx(r0 + 5 + rr, tA, tB);
        emit_rowx((rr == 2) ? rb2 : rb3, tA, tB, v);
      }
      __syncthreads();
    }

    int n0 = rb4, n1 = rb5, n2 = rb0, n3 = rb1, n4 = rb2, n5 = rb3;
    rb0 = n0; rb1 = n1; rb2 = n2; rb3 = n3; rb4 = n4; rb5 = n5;
  }
}

// ---------------------------------------------------------------------------
// conv2k: 2-row-tile conv2 (R15, unchanged; ~108us). Old k^(P&7) hash —
//   its u32x4 chunk-owner staging measured 0 conflicts.
// ---------------------------------------------------------------------------
__global__ __launch_bounds__(448, 2) void conv2k(
    const unsigned short* __restrict__ src,   // y1 bf16 NHWC
    const unsigned short* __restrict__ wP,
    const float* __restrict__ scale, const float* __restrict__ shift,
    const float* __restrict__ aP,
    float* __restrict__ dstf,
    const float* __restrict__ resid)
{
  constexpr int RS   = 114 * 128;   // 14592
  constexpr int WOFF = 4 * RS;      // 58368
  __shared__ __align__(16) unsigned char lds[WOFF + 73728];  // 132096

  const int t = threadIdx.x;
  const int b = blockIdx.x;
  const int n = b >> 2, q = b & 3;
  const int qbase = q * 28;
  const size_t ibase = (size_t)n * HWp;

  const int wv = t >> 6, l = t & 63;
  const int lo = l & 15, grp = l >> 4;

#pragma unroll
  for (int it = 0; it < 11; ++it) {
    int idx = t + it * 448;
    if (it < 10 || idx < 4608) {
      u32x4 v = *reinterpret_cast<const u32x4*>(wP + idx * 8);
      *reinterpret_cast<u32x4*>(&lds[WOFF + idx * 16]) = v;
    }
  }
  if (t < 64) {
    int r = t >> 4, P = ((t >> 3) & 1) ? 113 : 0, k = t & 7;
    u32x4 z = {0u, 0u, 0u, 0u};
    *reinterpret_cast<u32x4*>(&lds[r * RS + P * 128 + ((k ^ (P & 7)) << 4)]) = z;
  }
#pragma unroll
  for (int it = 0; it < 8; ++it) {
    int r = it >> 1;
    int rem = t + (it & 1) * 448;
    int w = rem >> 3, k = rem & 7;
    int hh = qbase - 1 + r;
    u32x4 val = {0u, 0u, 0u, 0u};
    if ((unsigned)hh < 112u)
      val = *reinterpret_cast<const u32x4*>(src + (ibase + hh * Wimg + w) * 64 + k * 8);
    int P = w + 1;
    *reinterpret_cast<u32x4*>(&lds[r * RS + P * 128 + ((k ^ (P & 7)) << 4)]) = val;
  }
  __syncthreads();

  int rb0 = 0 * RS, rb1 = 1 * RS, rb2 = 2 * RS, rb3 = 3 * RS;

  for (int T = 0; T < 14; ++T) {
    const int r0 = qbase + T * 2;

    float rres[2][2][4];
#pragma unroll
    for (int c = 0; c < 2; ++c)
#pragma unroll
      for (int p = 0; p < 2; ++p)
#pragma unroll
        for (int j = 0; j < 4; ++j) {
          size_t idx = ((size_t)(n * 64 + c * 16 + grp * 4 + j) * Himg + (r0 + p)) * Wimg
                       + wv * 16 + lo;
          rres[c][p][j] = resid[idx];
        }

    u32x4 preg[4];
    if (T < 13) {
#pragma unroll
      for (int it = 0; it < 4; ++it) {
        int j = it >> 1;
        int rem = t + (it & 1) * 448;
        int w = rem >> 3, k = rem & 7;
        int hh = r0 + 3 + j;
        u32x4 val = {0u, 0u, 0u, 0u};
        if (hh < 112)
          val = *reinterpret_cast<const u32x4*>(src + (ibase + hh * Wimg + w) * 64 + k * 8);
        preg[it] = val;
      }
    }
    __builtin_amdgcn_sched_barrier(0);

    f32x4 acc[4][2];
#pragma unroll
    for (int c = 0; c < 4; ++c)
#pragma unroll
      for (int p = 0; p < 2; ++p) {
        f32x4 z = {0.f, 0.f, 0.f, 0.f};
        acc[c][p] = z;
      }

#pragma unroll
    for (int s = 0; s < 18; ++s) {
      const int tap = s >> 1, ks = s & 1;
      const int dh = tap / 3, dw = tap - dh * 3;
      bf16x8 wf[4], pf[2];
#pragma unroll
      for (int c = 0; c < 4; ++c)
        wf[c] = *reinterpret_cast<const bf16x8*>(&lds[WOFF + (s * 4 + c) * 1024 + l * 16]);
      const int Pr = wv * 16 + lo + dw;
      const int c8 = (ks << 2) | grp;
      const int pbyte = Pr * 128 + ((c8 ^ (Pr & 7)) << 4);
#pragma unroll
      for (int p = 0; p < 2; ++p) {
        const int rr = p + dh;
        const int rbr = (rr == 0) ? rb0 : (rr == 1) ? rb1 : (rr == 2) ? rb2 : rb3;
        pf[p] = *reinterpret_cast<const bf16x8*>(&lds[rbr + pbyte]);
      }
#pragma unroll
      for (int c = 0; c < 4; ++c)
#pragma unroll
        for (int p = 0; p < 2; ++p)
          acc[c][p] = __builtin_amdgcn_mfma_f32_16x16x32_bf16(wf[c], pf[p], acc[c][p], 0, 0, 0);
    }

#pragma unroll
    for (int c = 0; c < 4; ++c) {
      const int co0 = c * 16 + grp * 4;
      float s_[4], h_[4], a_[4];
#pragma unroll
      for (int j = 0; j < 4; ++j) {
        s_[j] = scale[co0 + j];
        h_[j] = shift[co0 + j];
        a_[j] = aP[co0 + j];
      }
      const int w = wv * 16 + lo;
#pragma unroll
      for (int p = 0; p < 2; ++p) {
        const int hh = r0 + p;
        f32x4 v = acc[c][p];
#pragma unroll
        for (int j = 0; j < 4; ++j) {
          size_t idx = ((size_t)(n * 64 + co0 + j) * Himg + hh) * Wimg + w;
          float res = (c < 2) ? rres[c & 1][p][j] : resid[idx];
          float vv = v[j] * s_[j] + h_[j] + res;
          vv = vv >= 0.f ? vv : vv * a_[j];
          dstf[idx] = vv;
        }
      }
    }

    if (T < 13) {
      __syncthreads();
#pragma unroll
      for (int it = 0; it < 4; ++it) {
        int j = it >> 1;
        int rem = t + (it & 1) * 448;
        int w = rem >> 3, k = rem & 7;
        int P = w + 1;
        const int dst = (j == 0) ? rb0 : rb1;
        *reinterpret_cast<u32x4*>(&lds[dst + P * 128 + ((k ^ (P & 7)) << 4)]) = preg[it];
      }
      __syncthreads();
    }

    int n0 = rb2, n1 = rb3, n2 = rb0, n3 = rb1;
    rb0 = n0; rb1 = n1; rb2 = n2; rb3 = n3;
  }
}

// ---------------------------------------------------------------------------
// scratch map:
//   d_ws [0 .. 102,760,448)     : y1 bf16 NHWC
//   d_ws [+0 .. +73,728)        : wt1 packed bf16
//   d_ws [+73,728 .. +147,456)  : wt2 packed bf16
//   d_ws [+147,456 .. +149,000) : prm f32 (384 floats)
// ---------------------------------------------------------------------------
extern "C" void kernel_launch(void* const* d_in, const int* in_sizes, int n_in,
                              void* d_out, int out_size, void* d_ws, size_t ws_size,
                              hipStream_t stream)
{
  const float* x  = (const float*)d_in[0];
  const float* w1 = (const float*)d_in[1];
  const float* w2 = (const float*)d_in[2];
  const float* g0 = (const float*)d_in[3];
  const float* b0 = (const float*)d_in[4];
  const float* m0 = (const float*)d_in[5];
  const float* v0 = (const float*)d_in[6];
  const float* g1 = (const float*)d_in[7];
  const float* b1 = (const float*)d_in[8];
  const float* m1 = (const float*)d_in[9];
  const float* v1 = (const float*)d_in[10];
  const float* g2 = (const float*)d_in[11];
  const float* b2 = (const float*)d_in[12];
  const float* m2 = (const float*)d_in[13];
  const float* v2 = (const float*)d_in[14];
  const float* a1 = (const float*)d_in[15];
  const float* a2 = (const float*)d_in[16];

  unsigned char* wsb = (unsigned char*)d_ws;
  unsigned short* y1  = (unsigned short*)wsb;
  unsigned short* wt1 = (unsigned short*)(wsb + 102760448);
  unsigned short* wt2 = (unsigned short*)(wsb + 102760448 + 73728);
  float* prm          = (float*)(wsb + 102760448 + 2 * 73728);

  prep_misc<<<16, 256, 0, stream>>>(w1, w2, g0, b0, m0, v0, g1, b1, m1, v1,
                                    g2, b2, m2, v2, wt1, wt2, prm);
  conv1k<<<256, 448, 0, stream>>>(x, wt1, prm, prm + 64, a1, prm + 256, prm + 320, y1);
  conv2k<<<256, 448, 0, stream>>>(y1, wt2, prm + 128, prm + 192, a2, (float*)d_out, x);
}

// Round 18
// 223.520 us; speedup vs baseline: 1.2937x; 1.1206x over previous
//
#include <hip/hip_runtime.h>

#define EPSV 1e-5f

typedef __bf16 bf16x8 __attribute__((ext_vector_type(8)));
typedef float f32x4 __attribute__((ext_vector_type(4)));
typedef unsigned int u32x4 __attribute__((ext_vector_type(4)));
typedef unsigned short u16x4 __attribute__((ext_vector_type(4)));

__device__ __forceinline__ unsigned short f2bf(float f) {
  return __builtin_bit_cast(unsigned short, static_cast<__bf16>(f));
}

// conv1 patch swizzle (R17): spreads the cs/wb scalar-write pattern over 8
// bank-slots; reads <=3-way. Conflicts 2.2M @4-row — not critical-path.
__device__ __forceinline__ int swzB(int P, int k) {
  return P * 128 + (((k ^ (P & 7) ^ ((P >> 2) & 7)) & 7) << 4);
}

constexpr int Himg = 112, Wimg = 112, HWp = Himg * Wimg;  // 12544

// ---------------------------------------------------------------------------
// prep_misc: pack weights into per-lane MFMA A-fragment order + BN scale/shift
//   for all three BNs. prm: [0)=s1 [64)=h1 [128)=s2 [192)=h2 [256)=s0 [320)=h0
// ---------------------------------------------------------------------------
__global__ __launch_bounds__(256) void prep_misc(
    const float* __restrict__ w1, const float* __restrict__ w2,
    const float* __restrict__ g0, const float* __restrict__ b0,
    const float* __restrict__ m0, const float* __restrict__ v0,
    const float* __restrict__ g1, const float* __restrict__ b1,
    const float* __restrict__ m1, const float* __restrict__ v1,
    const float* __restrict__ g2, const float* __restrict__ b2,
    const float* __restrict__ m2, const float* __restrict__ v2,
    unsigned short* __restrict__ wt1, unsigned short* __restrict__ wt2,
    float* __restrict__ prm)
{
  int id = blockIdx.x * 256 + threadIdx.x;
  for (int i = id; i < 9 * 2 * 4 * 512; i += gridDim.x * 256) {
    int j   = i & 7;
    int l   = (i >> 3) & 63;
    int c   = (i >> 9) & 3;
    int ks  = (i >> 11) & 1;
    int tap = i >> 12;
    int co  = c * 16 + (l & 15);
    int ci  = ks * 32 + (l >> 4) * 8 + j;
    int kh  = tap / 3, kw = tap - kh * 3;
    int src = ((co * 64 + ci) * 3 + kh) * 3 + kw;
    wt1[i] = f2bf(w1[src]);
    wt2[i] = f2bf(w2[src]);
  }
  if (id < 64) {
    float s1 = g1[id] * rsqrtf(v1[id] + EPSV);
    prm[id]      = s1;
    prm[64 + id] = b1[id] - m1[id] * s1;
    float s2 = g2[id] * rsqrtf(v2[id] + EPSV);
    prm[128 + id] = s2;
    prm[192 + id] = b2[id] - m2[id] * s2;
    float s0 = g0[id] * rsqrtf(v0[id] + EPSV);
    prm[256 + id] = s0;
    prm[320 + id] = b0[id] - m0[id] * s0;
  }
}

// ---------------------------------------------------------------------------
// conv1k: conv1 ported to the conv2k 2-ROW-TILE structure (R17 post-mortem:
//   4-row conv1k=140us vs 2-row conv2k=105us at same bytes — tile granularity
//   is the lever; conflicts were not).
//   Persistent 256 blocks, 448 thr; block owns (n=b>>2, rows q*28..+27):
//   14 tiles of 2 rows. LDS 132096 B: ring 4 x [114][128B] (swzB) + weights.
//   Staging: R14 coalesced cs/wb map (28 lanes per 448B plane run, f32x4),
//   BN0 fused, both next rows prefetched into regs (32 VGPR).
// ---------------------------------------------------------------------------
__global__ __launch_bounds__(448, 2) void conv1k(
    const float* __restrict__ xsrc,
    const unsigned short* __restrict__ wP,
    const float* __restrict__ scale, const float* __restrict__ shift,
    const float* __restrict__ aP,
    const float* __restrict__ bn0sc, const float* __restrict__ bn0sh,
    unsigned short* __restrict__ dstb)
{
  constexpr int RS   = 114 * 128;   // 14592
  constexpr int WOFF = 4 * RS;      // 58368
  __shared__ __align__(16) unsigned char lds[WOFF + 73728];  // 132096

  const int t = threadIdx.x;
  const int b = blockIdx.x;
  const int n = b >> 2, q = b & 3;
  const int qbase = q * 28;
  const size_t ibase = (size_t)n * HWp;
  const float* xn = xsrc + (size_t)n * 64 * HWp;

  const int wv = t >> 6, l = t & 63;
  const int lo = l & 15, grp = l >> 4;

  // staging map (R14): cs = channel-quad owner, wb = pixel-quad within row
  const int cs = t / 28, wb = t - cs * 28;
  const int w0s = wb * 4;
  float scv[4], shv[4];
#pragma unroll
  for (int cc = 0; cc < 4; ++cc) {
    scv[cc] = bn0sc[cs * 4 + cc];
    shv[cc] = bn0sh[cs * 4 + cc];
  }

  auto load_rowx = [&](int hh, f32x4 (&A)[2], f32x4 (&B)[2]) -> bool {
    bool valid = (unsigned)hh < 112u;
#pragma unroll
    for (int u = 0; u < 2; ++u) {
      f32x4 z = {0.f, 0.f, 0.f, 0.f};
      A[u] = z; B[u] = z;
      if (valid) {
        const int ca = cs * 4 + u * 2;
        A[u] = *reinterpret_cast<const f32x4*>(xn + (size_t)ca * HWp + hh * Wimg + w0s);
        B[u] = *reinterpret_cast<const f32x4*>(xn + (size_t)(ca + 1) * HWp + hh * Wimg + w0s);
      }
    }
    return valid;
  };
  auto emit_rowx = [&](int rbX, const f32x4 (&A)[2], const f32x4 (&B)[2], bool valid) {
#pragma unroll
    for (int u = 0; u < 2; ++u) {
      const int ca = cs * 4 + u * 2;
      const int kk = ca >> 3;
      const int off = (ca & 7) * 2;
#pragma unroll
      for (int j = 0; j < 4; ++j) {
        float fa = valid ? A[u][j] * scv[u * 2] + shv[u * 2] : 0.f;
        float fb = valid ? B[u][j] * scv[u * 2 + 1] + shv[u * 2 + 1] : 0.f;
        unsigned int pk = (unsigned int)f2bf(fa) | ((unsigned int)f2bf(fb) << 16);
        int P = w0s + j + 1;
        *reinterpret_cast<unsigned int*>(&lds[rbX + swzB(P, kk) + off]) = pk;
      }
    }
  };

  // weights full (once), linear region
#pragma unroll
  for (int it = 0; it < 11; ++it) {
    int idx = t + it * 448;
    if (it < 10 || idx < 4608) {
      u32x4 v = *reinterpret_cast<const u32x4*>(wP + idx * 8);
      *reinterpret_cast<u32x4*>(&lds[WOFF + idx * 16]) = v;
    }
  }
  // halo zero: wpad cols (P=0,113), 4 slots — swzB hash
  if (t < 64) {
    int r = t >> 4, P = ((t >> 3) & 1) ? 113 : 0, k = t & 7;
    u32x4 z = {0u, 0u, 0u, 0u};
    *reinterpret_cast<u32x4*>(&lds[r * RS + swzB(P, k)]) = z;
  }
  // rows qbase-1 .. qbase+2 -> slots 0..3
#pragma unroll
  for (int r = 0; r < 4; ++r) {
    f32x4 A[2], B[2];
    bool v = load_rowx(qbase - 1 + r, A, B);
    emit_rowx(r * RS, A, B, v);
  }
  __syncthreads();

  int rb0 = 0 * RS, rb1 = 1 * RS, rb2 = 2 * RS, rb3 = 3 * RS;

  for (int T = 0; T < 14; ++T) {
    const int r0 = qbase + T * 2;

    // prefetch both next rows (r0+3, r0+4) into regs
    f32x4 pA[2][2], pB[2][2];
    bool pv[2];
    if (T < 13) {
#pragma unroll
      for (int rr = 0; rr < 2; ++rr)
        pv[rr] = load_rowx(r0 + 3 + rr, pA[rr], pB[rr]);
    }

    f32x4 acc[4][2];
#pragma unroll
    for (int c = 0; c < 4; ++c)
#pragma unroll
      for (int p = 0; p < 2; ++p) {
        f32x4 z = {0.f, 0.f, 0.f, 0.f};
        acc[c][p] = z;
      }

    // K-loop: 18 steps, pure LDS + MFMA
#pragma unroll
    for (int s = 0; s < 18; ++s) {
      const int tap = s >> 1, ks = s & 1;
      const int dh = tap / 3, dw = tap - dh * 3;
      bf16x8 wf[4], pf[2];
#pragma unroll
      for (int c = 0; c < 4; ++c)
        wf[c] = *reinterpret_cast<const bf16x8*>(&lds[WOFF + (s * 4 + c) * 1024 + l * 16]);
      const int Pr = wv * 16 + lo + dw;
      const int c8 = (ks << 2) | grp;
      const int pbyte = swzB(Pr, c8);
#pragma unroll
      for (int p = 0; p < 2; ++p) {
        const int rr = p + dh;             // 0..3
        const int rbr = (rr == 0) ? rb0 : (rr == 1) ? rb1 : (rr == 2) ? rb2 : rb3;
        pf[p] = *reinterpret_cast<const bf16x8*>(&lds[rbr + pbyte]);
      }
#pragma unroll
      for (int c = 0; c < 4; ++c)
#pragma unroll
        for (int p = 0; p < 2; ++p)
          acc[c][p] = __builtin_amdgcn_mfma_f32_16x16x32_bf16(wf[c], pf[p], acc[c][p], 0, 0, 0);
    }

    // epilogue: rows r0, r0+1 -> y1 bf16 NHWC
#pragma unroll
    for (int c = 0; c < 4; ++c) {
      const int co0 = c * 16 + grp * 4;
      float s_[4], h_[4], a_[4];
#pragma unroll
      for (int j = 0; j < 4; ++j) {
        s_[j] = scale[co0 + j];
        h_[j] = shift[co0 + j];
        a_[j] = aP[co0 + j];
      }
      const int w = wv * 16 + lo;
#pragma unroll
      for (int p = 0; p < 2; ++p) {
        const int hh = r0 + p;
        f32x4 v = acc[c][p];
        u16x4 u;
#pragma unroll
        for (int j = 0; j < 4; ++j) {
          float vv = v[j] * s_[j] + h_[j];
          vv = vv >= 0.f ? vv : vv * a_[j];
          u[j] = f2bf(vv);
        }
        *reinterpret_cast<u16x4*>(dstb + (ibase + hh * Wimg + w) * 64 + co0) = u;
      }
    }

    // restage ring
    if (T < 13) {
      __syncthreads();
      emit_rowx(rb0, pA[0], pB[0], pv[0]);
      emit_rowx(rb1, pA[1], pB[1], pv[1]);
      __syncthreads();
    }

    // rotate ring by 2 rows: (0,1,2,3) -> (2,3,0,1)
    int n0 = rb2, n1 = rb3, n2 = rb0, n3 = rb1;
    rb0 = n0; rb1 = n1; rb2 = n2; rb3 = n3;
  }
}

// ---------------------------------------------------------------------------
// conv2k: 2-row-tile conv2 (R15/R17, unchanged; ~105us).
// ---------------------------------------------------------------------------
__global__ __launch_bounds__(448, 2) void conv2k(
    const unsigned short* __restrict__ src,   // y1 bf16 NHWC
    const unsigned short* __restrict__ wP,
    const float* __restrict__ scale, const float* __restrict__ shift,
    const float* __restrict__ aP,
    float* __restrict__ dstf,
    const float* __restrict__ resid)
{
  constexpr int RS   = 114 * 128;   // 14592
  constexpr int WOFF = 4 * RS;      // 58368
  __shared__ __align__(16) unsigned char lds[WOFF + 73728];  // 132096

  const int t = threadIdx.x;
  const int b = blockIdx.x;
  const int n = b >> 2, q = b & 3;
  const int qbase = q * 28;
  const size_t ibase = (size_t)n * HWp;

  const int wv = t >> 6, l = t & 63;
  const int lo = l & 15, grp = l >> 4;

#pragma unroll
  for (int it = 0; it < 11; ++it) {
    int idx = t + it * 448;
    if (it < 10 || idx < 4608) {
      u32x4 v = *reinterpret_cast<const u32x4*>(wP + idx * 8);
      *reinterpret_cast<u32x4*>(&lds[WOFF + idx * 16]) = v;
    }
  }
  if (t < 64) {
    int r = t >> 4, P = ((t >> 3) & 1) ? 113 : 0, k = t & 7;
    u32x4 z = {0u, 0u, 0u, 0u};
    *reinterpret_cast<u32x4*>(&lds[r * RS + P * 128 + ((k ^ (P & 7)) << 4)]) = z;
  }
#pragma unroll
  for (int it = 0; it < 8; ++it) {
    int r = it >> 1;
    int rem = t + (it & 1) * 448;
    int w = rem >> 3, k = rem & 7;
    int hh = qbase - 1 + r;
    u32x4 val = {0u, 0u, 0u, 0u};
    if ((unsigned)hh < 112u)
      val = *reinterpret_cast<const u32x4*>(src + (ibase + hh * Wimg + w) * 64 + k * 8);
    int P = w + 1;
    *reinterpret_cast<u32x4*>(&lds[r * RS + P * 128 + ((k ^ (P & 7)) << 4)]) = val;
  }
  __syncthreads();

  int rb0 = 0 * RS, rb1 = 1 * RS, rb2 = 2 * RS, rb3 = 3 * RS;

  for (int T = 0; T < 14; ++T) {
    const int r0 = qbase + T * 2;

    float rres[2][2][4];
#pragma unroll
    for (int c = 0; c < 2; ++c)
#pragma unroll
      for (int p = 0; p < 2; ++p)
#pragma unroll
        for (int j = 0; j < 4; ++j) {
          size_t idx = ((size_t)(n * 64 + c * 16 + grp * 4 + j) * Himg + (r0 + p)) * Wimg
                       + wv * 16 + lo;
          rres[c][p][j] = resid[idx];
        }

    u32x4 preg[4];
    if (T < 13) {
#pragma unroll
      for (int it = 0; it < 4; ++it) {
        int j = it >> 1;
        int rem = t + (it & 1) * 448;
        int w = rem >> 3, k = rem & 7;
        int hh = r0 + 3 + j;
        u32x4 val = {0u, 0u, 0u, 0u};
        if (hh < 112)
          val = *reinterpret_cast<const u32x4*>(src + (ibase + hh * Wimg + w) * 64 + k * 8);
        preg[it] = val;
      }
    }
    __builtin_amdgcn_sched_barrier(0);

    f32x4 acc[4][2];
#pragma unroll
    for (int c = 0; c < 4; ++c)
#pragma unroll
      for (int p = 0; p < 2; ++p) {
        f32x4 z = {0.f, 0.f, 0.f, 0.f};
        acc[c][p] = z;
      }

#pragma unroll
    for (int s = 0; s < 18; ++s) {
      const int tap = s >> 1, ks = s & 1;
      const int dh = tap / 3, dw = tap - dh * 3;
      bf16x8 wf[4], pf[2];
#pragma unroll
      for (int c = 0; c < 4; ++c)
        wf[c] = *reinterpret_cast<const bf16x8*>(&lds[WOFF + (s * 4 + c) * 1024 + l * 16]);
      const int Pr = wv * 16 + lo + dw;
      const int c8 = (ks << 2) | grp;
      const int pbyte = Pr * 128 + ((c8 ^ (Pr & 7)) << 4);
#pragma unroll
      for (int p = 0; p < 2; ++p) {
        const int rr = p + dh;
        const int rbr = (rr == 0) ? rb0 : (rr == 1) ? rb1 : (rr == 2) ? rb2 : rb3;
        pf[p] = *reinterpret_cast<const bf16x8*>(&lds[rbr + pbyte]);
      }
#pragma unroll
      for (int c = 0; c < 4; ++c)
#pragma unroll
        for (int p = 0; p < 2; ++p)
          acc[c][p] = __builtin_amdgcn_mfma_f32_16x16x32_bf16(wf[c], pf[p], acc[c][p], 0, 0, 0);
    }

#pragma unroll
    for (int c = 0; c < 4; ++c) {
      const int co0 = c * 16 + grp * 4;
      float s_[4], h_[4], a_[4];
#pragma unroll
      for (int j = 0; j < 4; ++j) {
        s_[j] = scale[co0 + j];
        h_[j] = shift[co0 + j];
        a_[j] = aP[co0 + j];
      }
      const int w = wv * 16 + lo;
#pragma unroll
      for (int p = 0; p < 2; ++p) {
        const int hh = r0 + p;
        f32x4 v = acc[c][p];
#pragma unroll
        for (int j = 0; j < 4; ++j) {
          size_t idx = ((size_t)(n * 64 + co0 + j) * Himg + hh) * Wimg + w;
          float res = (c < 2) ? rres[c & 1][p][j] : resid[idx];
          float vv = v[j] * s_[j] + h_[j] + res;
          vv = vv >= 0.f ? vv : vv * a_[j];
          dstf[idx] = vv;
        }
      }
    }

    if (T < 13) {
      __syncthreads();
#pragma unroll
      for (int it = 0; it < 4; ++it) {
        int j = it >> 1;
        int rem = t + (it & 1) * 448;
        int w = rem >> 3, k = rem & 7;
        int P = w + 1;
        const int dst = (j == 0) ? rb0 : rb1;
        *reinterpret_cast<u32x4*>(&lds[dst + P * 128 + ((k ^ (P & 7)) << 4)]) = preg[it];
      }
      __syncthreads();
    }

    int n0 = rb2, n1 = rb3, n2 = rb0, n3 = rb1;
    rb0 = n0; rb1 = n1; rb2 = n2; rb3 = n3;
  }
}

// ---------------------------------------------------------------------------
// scratch map:
//   d_ws [0 .. 102,760,448)     : y1 bf16 NHWC
//   d_ws [+0 .. +73,728)        : wt1 packed bf16
//   d_ws [+73,728 .. +147,456)  : wt2 packed bf16
//   d_ws [+147,456 .. +149,000) : prm f32 (384 floats)
// ---------------------------------------------------------------------------
extern "C" void kernel_launch(void* const* d_in, const int* in_sizes, int n_in,
                              void* d_out, int out_size, void* d_ws, size_t ws_size,
                              hipStream_t stream)
{
  const float* x  = (const float*)d_in[0];
  const float* w1 = (const float*)d_in[1];
  const float* w2 = (const float*)d_in[2];
  const float* g0 = (const float*)d_in[3];
  const float* b0 = (const float*)d_in[4];
  const float* m0 = (const float*)d_in[5];
  const float* v0 = (const float*)d_in[6];
  const float* g1 = (const float*)d_in[7];
  const float* b1 = (const float*)d_in[8];
  const float* m1 = (const float*)d_in[9];
  const float* v1 = (const float*)d_in[10];
  const float* g2 = (const float*)d_in[11];
  const float* b2 = (const float*)d_in[12];
  const float* m2 = (const float*)d_in[13];
  const float* v2 = (const float*)d_in[14];
  const float* a1 = (const float*)d_in[15];
  const float* a2 = (const float*)d_in[16];

  unsigned char* wsb = (unsigned char*)d_ws;
  unsigned short* y1  = (unsigned short*)wsb;
  unsigned short* wt1 = (unsigned short*)(wsb + 102760448);
  unsigned short* wt2 = (unsigned short*)(wsb + 102760448 + 73728);
  float* prm          = (float*)(wsb + 102760448 + 2 * 73728);

  prep_misc<<<16, 256, 0, stream>>>(w1, w2, g0, b0, m0, v0, g1, b1, m1, v1,
                                    g2, b2, m2, v2, wt1, wt2, prm);
  conv1k<<<256, 448, 0, stream>>>(x, wt1, prm, prm + 64, a1, prm + 256, prm + 320, y1);
  conv2k<<<256, 448, 0, stream>>>(y1, wt2, prm + 128, prm + 192, a2, (float*)d_out, x);
}

// Round 19
// 208.186 us; speedup vs baseline: 1.3890x; 1.0737x over previous
//
#include <hip/hip_runtime.h>

#define EPSV 1e-5f

typedef __bf16 bf16x8 __attribute__((ext_vector_type(8)));
typedef float f32x4 __attribute__((ext_vector_type(4)));
typedef unsigned int u32x4 __attribute__((ext_vector_type(4)));
typedef unsigned short u16x4 __attribute__((ext_vector_type(4)));

__device__ __forceinline__ unsigned short f2bf(float f) {
  return __builtin_bit_cast(unsigned short, static_cast<__bf16>(f));
}

// conv1 patch swizzle (R17)
__device__ __forceinline__ int swzB(int P, int k) {
  return P * 128 + (((k ^ (P & 7) ^ ((P >> 2) & 7)) & 7) << 4);
}

constexpr int Himg = 112, Wimg = 112, HWp = Himg * Wimg;  // 12544

// ---------------------------------------------------------------------------
// prep_misc: pack weights + BN scale/shift for all three BNs.
//   prm: [0)=s1 [64)=h1 [128)=s2 [192)=h2 [256)=s0 [320)=h0
// ---------------------------------------------------------------------------
__global__ __launch_bounds__(256) void prep_misc(
    const float* __restrict__ w1, const float* __restrict__ w2,
    const float* __restrict__ g0, const float* __restrict__ b0,
    const float* __restrict__ m0, const float* __restrict__ v0,
    const float* __restrict__ g1, const float* __restrict__ b1,
    const float* __restrict__ m1, const float* __restrict__ v1,
    const float* __restrict__ g2, const float* __restrict__ b2,
    const float* __restrict__ m2, const float* __restrict__ v2,
    unsigned short* __restrict__ wt1, unsigned short* __restrict__ wt2,
    float* __restrict__ prm)
{
  int id = blockIdx.x * 256 + threadIdx.x;
  for (int i = id; i < 9 * 2 * 4 * 512; i += gridDim.x * 256) {
    int j   = i & 7;
    int l   = (i >> 3) & 63;
    int c   = (i >> 9) & 3;
    int ks  = (i >> 11) & 1;
    int tap = i >> 12;
    int co  = c * 16 + (l & 15);
    int ci  = ks * 32 + (l >> 4) * 8 + j;
    int kh  = tap / 3, kw = tap - kh * 3;
    int src = ((co * 64 + ci) * 3 + kh) * 3 + kw;
    wt1[i] = f2bf(w1[src]);
    wt2[i] = f2bf(w2[src]);
  }
  if (id < 64) {
    float s1 = g1[id] * rsqrtf(v1[id] + EPSV);
    prm[id]      = s1;
    prm[64 + id] = b1[id] - m1[id] * s1;
    float s2 = g2[id] * rsqrtf(v2[id] + EPSV);
    prm[128 + id] = s2;
    prm[192 + id] = b2[id] - m2[id] * s2;
    float s0 = g0[id] * rsqrtf(v0[id] + EPSV);
    prm[256 + id] = s0;
    prm[320 + id] = b0[id] - m0[id] * s0;
  }
}

// ---------------------------------------------------------------------------
// conv1k: 2-row tiles + 6-SLOT RING, ONE barrier/tile.
//   Tile T reads slots 0-3 (rows r0-1..r0+2); emit writes slots 4,5
//   (rows r0+3,r0+4) — disjoint, so no pre-emit barrier needed; single
//   __syncthreads() publishes before rotate-by-2 (new i = old (i+2)%6).
//   Staging: R14 coalesced cs/wb map, BN0 fused, swzB hash.
// ---------------------------------------------------------------------------
__global__ __launch_bounds__(448, 2) void conv1k(
    const float* __restrict__ xsrc,
    const unsigned short* __restrict__ wP,
    const float* __restrict__ scale, const float* __restrict__ shift,
    const float* __restrict__ aP,
    const float* __restrict__ bn0sc, const float* __restrict__ bn0sh,
    unsigned short* __restrict__ dstb)
{
  constexpr int RS   = 114 * 128;   // 14592
  constexpr int WOFF = 6 * RS;      // 87552
  __shared__ __align__(16) unsigned char lds[WOFF + 73728];  // 161280

  const int t = threadIdx.x;
  const int b = blockIdx.x;
  const int n = b >> 2, q = b & 3;
  const int qbase = q * 28;
  const size_t ibase = (size_t)n * HWp;
  const float* xn = xsrc + (size_t)n * 64 * HWp;

  const int wv = t >> 6, l = t & 63;
  const int lo = l & 15, grp = l >> 4;

  const int cs = t / 28, wb = t - cs * 28;
  const int w0s = wb * 4;
  float scv[4], shv[4];
#pragma unroll
  for (int cc = 0; cc < 4; ++cc) {
    scv[cc] = bn0sc[cs * 4 + cc];
    shv[cc] = bn0sh[cs * 4 + cc];
  }

  auto load_rowx = [&](int hh, f32x4 (&A)[2], f32x4 (&B)[2]) -> bool {
    bool valid = (unsigned)hh < 112u;
#pragma unroll
    for (int u = 0; u < 2; ++u) {
      f32x4 z = {0.f, 0.f, 0.f, 0.f};
      A[u] = z; B[u] = z;
      if (valid) {
        const int ca = cs * 4 + u * 2;
        A[u] = *reinterpret_cast<const f32x4*>(xn + (size_t)ca * HWp + hh * Wimg + w0s);
        B[u] = *reinterpret_cast<const f32x4*>(xn + (size_t)(ca + 1) * HWp + hh * Wimg + w0s);
      }
    }
    return valid;
  };
  auto emit_rowx = [&](int rbX, const f32x4 (&A)[2], const f32x4 (&B)[2], bool valid) {
#pragma unroll
    for (int u = 0; u < 2; ++u) {
      const int ca = cs * 4 + u * 2;
      const int kk = ca >> 3;
      const int off = (ca & 7) * 2;
#pragma unroll
      for (int j = 0; j < 4; ++j) {
        float fa = valid ? A[u][j] * scv[u * 2] + shv[u * 2] : 0.f;
        float fb = valid ? B[u][j] * scv[u * 2 + 1] + shv[u * 2 + 1] : 0.f;
        unsigned int pk = (unsigned int)f2bf(fa) | ((unsigned int)f2bf(fb) << 16);
        int P = w0s + j + 1;
        *reinterpret_cast<unsigned int*>(&lds[rbX + swzB(P, kk) + off]) = pk;
      }
    }
  };

  // weights full (once), linear region
#pragma unroll
  for (int it = 0; it < 11; ++it) {
    int idx = t + it * 448;
    if (it < 10 || idx < 4608) {
      u32x4 v = *reinterpret_cast<const u32x4*>(wP + idx * 8);
      *reinterpret_cast<u32x4*>(&lds[WOFF + idx * 16]) = v;
    }
  }
  // halo zero: wpad cols (P=0,113), 6 slots — swzB hash
  if (t < 96) {
    int r = t >> 4, P = ((t >> 3) & 1) ? 113 : 0, k = t & 7;
    u32x4 z = {0u, 0u, 0u, 0u};
    *reinterpret_cast<u32x4*>(&lds[r * RS + swzB(P, k)]) = z;
  }
  // rows qbase-1 .. qbase+2 -> slots 0..3
#pragma unroll
  for (int r = 0; r < 4; ++r) {
    f32x4 A[2], B[2];
    bool v = load_rowx(qbase - 1 + r, A, B);
    emit_rowx(r * RS, A, B, v);
  }
  __syncthreads();

  int rb0 = 0 * RS, rb1 = 1 * RS, rb2 = 2 * RS, rb3 = 3 * RS, rb4 = 4 * RS, rb5 = 5 * RS;

  for (int T = 0; T < 14; ++T) {
    const int r0 = qbase + T * 2;

    // prefetch rows r0+3, r0+4 into regs
    f32x4 pA[2][2], pB[2][2];
    bool pv[2];
    if (T < 13) {
#pragma unroll
      for (int rr = 0; rr < 2; ++rr)
        pv[rr] = load_rowx(r0 + 3 + rr, pA[rr], pB[rr]);
    }

    f32x4 acc[4][2];
#pragma unroll
    for (int c = 0; c < 4; ++c)
#pragma unroll
      for (int p = 0; p < 2; ++p) {
        f32x4 z = {0.f, 0.f, 0.f, 0.f};
        acc[c][p] = z;
      }

    // K-loop: 18 steps, reads slots 0..3 only
#pragma unroll
    for (int s = 0; s < 18; ++s) {
      const int tap = s >> 1, ks = s & 1;
      const int dh = tap / 3, dw = tap - dh * 3;
      bf16x8 wf[4], pf[2];
#pragma unroll
      for (int c = 0; c < 4; ++c)
        wf[c] = *reinterpret_cast<const bf16x8*>(&lds[WOFF + (s * 4 + c) * 1024 + l * 16]);
      const int Pr = wv * 16 + lo + dw;
      const int c8 = (ks << 2) | grp;
      const int pbyte = swzB(Pr, c8);
#pragma unroll
      for (int p = 0; p < 2; ++p) {
        const int rr = p + dh;             // 0..3
        const int rbr = (rr == 0) ? rb0 : (rr == 1) ? rb1 : (rr == 2) ? rb2 : rb3;
        pf[p] = *reinterpret_cast<const bf16x8*>(&lds[rbr + pbyte]);
      }
#pragma unroll
      for (int c = 0; c < 4; ++c)
#pragma unroll
        for (int p = 0; p < 2; ++p)
          acc[c][p] = __builtin_amdgcn_mfma_f32_16x16x32_bf16(wf[c], pf[p], acc[c][p], 0, 0, 0);
    }

    // epilogue: rows r0, r0+1 -> y1 bf16 NHWC
#pragma unroll
    for (int c = 0; c < 4; ++c) {
      const int co0 = c * 16 + grp * 4;
      float s_[4], h_[4], a_[4];
#pragma unroll
      for (int j = 0; j < 4; ++j) {
        s_[j] = scale[co0 + j];
        h_[j] = shift[co0 + j];
        a_[j] = aP[co0 + j];
      }
      const int w = wv * 16 + lo;
#pragma unroll
      for (int p = 0; p < 2; ++p) {
        const int hh = r0 + p;
        f32x4 v = acc[c][p];
        u16x4 u;
#pragma unroll
        for (int j = 0; j < 4; ++j) {
          float vv = v[j] * s_[j] + h_[j];
          vv = vv >= 0.f ? vv : vv * a_[j];
          u[j] = f2bf(vv);
        }
        *reinterpret_cast<u16x4*>(dstb + (ibase + hh * Wimg + w) * 64 + co0) = u;
      }
    }

    // emit to spare slots 4,5 (disjoint from read slots 0-3) + ONE barrier
    if (T < 13) {
      emit_rowx(rb4, pA[0], pB[0], pv[0]);
      emit_rowx(rb5, pA[1], pB[1], pv[1]);
      __syncthreads();
    }

    // rotate by 2: new(0..5) = old(2,3,4,5,0,1)
    int n0 = rb2, n1 = rb3, n2 = rb4, n3 = rb5, n4 = rb0, n5 = rb1;
    rb0 = n0; rb1 = n1; rb2 = n2; rb3 = n3; rb4 = n4; rb5 = n5;
  }
}

// ---------------------------------------------------------------------------
// conv2k: 2-row tiles + 6-SLOT RING (one barrier/tile) + FULL resid prefetch
//   (rres[4][2][4] = 32 regs; at R18's VGPR=96 there is headroom under 128).
// ---------------------------------------------------------------------------
__global__ __launch_bounds__(448, 2) void conv2k(
    const unsigned short* __restrict__ src,   // y1 bf16 NHWC
    const unsigned short* __restrict__ wP,
    const float* __restrict__ scale, const float* __restrict__ shift,
    const float* __restrict__ aP,
    float* __restrict__ dstf,
    const float* __restrict__ resid)
{
  constexpr int RS   = 114 * 128;   // 14592
  constexpr int WOFF = 6 * RS;      // 87552
  __shared__ __align__(16) unsigned char lds[WOFF + 73728];  // 161280

  const int t = threadIdx.x;
  const int b = blockIdx.x;
  const int n = b >> 2, q = b & 3;
  const int qbase = q * 28;
  const size_t ibase = (size_t)n * HWp;

  const int wv = t >> 6, l = t & 63;
  const int lo = l & 15, grp = l >> 4;

#pragma unroll
  for (int it = 0; it < 11; ++it) {
    int idx = t + it * 448;
    if (it < 10 || idx < 4608) {
      u32x4 v = *reinterpret_cast<const u32x4*>(wP + idx * 8);
      *reinterpret_cast<u32x4*>(&lds[WOFF + idx * 16]) = v;
    }
  }
  // halo zero: 6 slots
  if (t < 96) {
    int r = t >> 4, P = ((t >> 3) & 1) ? 113 : 0, k = t & 7;
    u32x4 z = {0u, 0u, 0u, 0u};
    *reinterpret_cast<u32x4*>(&lds[r * RS + P * 128 + ((k ^ (P & 7)) << 4)]) = z;
  }
  // rows qbase-1 .. qbase+2 -> slots 0..3
#pragma unroll
  for (int it = 0; it < 8; ++it) {
    int r = it >> 1;
    int rem = t + (it & 1) * 448;
    int w = rem >> 3, k = rem & 7;
    int hh = qbase - 1 + r;
    u32x4 val = {0u, 0u, 0u, 0u};
    if ((unsigned)hh < 112u)
      val = *reinterpret_cast<const u32x4*>(src + (ibase + hh * Wimg + w) * 64 + k * 8);
    int P = w + 1;
    *reinterpret_cast<u32x4*>(&lds[r * RS + P * 128 + ((k ^ (P & 7)) << 4)]) = val;
  }
  __syncthreads();

  int rb0 = 0 * RS, rb1 = 1 * RS, rb2 = 2 * RS, rb3 = 3 * RS, rb4 = 4 * RS, rb5 = 5 * RS;

  for (int T = 0; T < 14; ++T) {
    const int r0 = qbase + T * 2;

    // FULL resid prefetch (32 f32): drains under the K-loop
    float rres[4][2][4];
#pragma unroll
    for (int c = 0; c < 4; ++c)
#pragma unroll
      for (int p = 0; p < 2; ++p)
#pragma unroll
        for (int j = 0; j < 4; ++j) {
          size_t idx = ((size_t)(n * 64 + c * 16 + grp * 4 + j) * Himg + (r0 + p)) * Wimg
                       + wv * 16 + lo;
          rres[c][p][j] = resid[idx];
        }

    u32x4 preg[4];
    if (T < 13) {
#pragma unroll
      for (int it = 0; it < 4; ++it) {
        int j = it >> 1;
        int rem = t + (it & 1) * 448;
        int w = rem >> 3, k = rem & 7;
        int hh = r0 + 3 + j;
        u32x4 val = {0u, 0u, 0u, 0u};
        if (hh < 112)
          val = *reinterpret_cast<const u32x4*>(src + (ibase + hh * Wimg + w) * 64 + k * 8);
        preg[it] = val;
      }
    }
    __builtin_amdgcn_sched_barrier(0);

    f32x4 acc[4][2];
#pragma unroll
    for (int c = 0; c < 4; ++c)
#pragma unroll
      for (int p = 0; p < 2; ++p) {
        f32x4 z = {0.f, 0.f, 0.f, 0.f};
        acc[c][p] = z;
      }

#pragma unroll
    for (int s = 0; s < 18; ++s) {
      const int tap = s >> 1, ks = s & 1;
      const int dh = tap / 3, dw = tap - dh * 3;
      bf16x8 wf[4], pf[2];
#pragma unroll
      for (int c = 0; c < 4; ++c)
        wf[c] = *reinterpret_cast<const bf16x8*>(&lds[WOFF + (s * 4 + c) * 1024 + l * 16]);
      const int Pr = wv * 16 + lo + dw;
      const int c8 = (ks << 2) | grp;
      const int pbyte = Pr * 128 + ((c8 ^ (Pr & 7)) << 4);
#pragma unroll
      for (int p = 0; p < 2; ++p) {
        const int rr = p + dh;
        const int rbr = (rr == 0) ? rb0 : (rr == 1) ? rb1 : (rr == 2) ? rb2 : rb3;
        pf[p] = *reinterpret_cast<const bf16x8*>(&lds[rbr + pbyte]);
      }
#pragma unroll
      for (int c = 0; c < 4; ++c)
#pragma unroll
        for (int p = 0; p < 2; ++p)
          acc[c][p] = __builtin_amdgcn_mfma_f32_16x16x32_bf16(wf[c], pf[p], acc[c][p], 0, 0, 0);
    }

#pragma unroll
    for (int c = 0; c < 4; ++c) {
      const int co0 = c * 16 + grp * 4;
      float s_[4], h_[4], a_[4];
#pragma unroll
      for (int j = 0; j < 4; ++j) {
        s_[j] = scale[co0 + j];
        h_[j] = shift[co0 + j];
        a_[j] = aP[co0 + j];
      }
      const int w = wv * 16 + lo;
#pragma unroll
      for (int p = 0; p < 2; ++p) {
        const int hh = r0 + p;
        f32x4 v = acc[c][p];
#pragma unroll
        for (int j = 0; j < 4; ++j) {
          size_t idx = ((size_t)(n * 64 + co0 + j) * Himg + hh) * Wimg + w;
          float vv = v[j] * s_[j] + h_[j] + rres[c][p][j];
          vv = vv >= 0.f ? vv : vv * a_[j];
          dstf[idx] = vv;
        }
      }
    }

    // emit to spare slots 4,5 + ONE barrier
    if (T < 13) {
#pragma unroll
      for (int it = 0; it < 4; ++it) {
        int j = it >> 1;
        int rem = t + (it & 1) * 448;
        int w = rem >> 3, k = rem & 7;
        int P = w + 1;
        const int dst = (j == 0) ? rb4 : rb5;
        *reinterpret_cast<u32x4*>(&lds[dst + P * 128 + ((k ^ (P & 7)) << 4)]) = preg[it];
      }
      __syncthreads();
    }

    // rotate by 2: new(0..5) = old(2,3,4,5,0,1)
    int n0 = rb2, n1 = rb3, n2 = rb4, n3 = rb5, n4 = rb0, n5 = rb1;
    rb0 = n0; rb1 = n1; rb2 = n2; rb3 = n3; rb4 = n4; rb5 = n5;
  }
}

// ---------------------------------------------------------------------------
// scratch map:
//   d_ws [0 .. 102,760,448)     : y1 bf16 NHWC
//   d_ws [+0 .. +73,728)        : wt1 packed bf16
//   d_ws [+73,728 .. +147,456)  : wt2 packed bf16
//   d_ws [+147,456 .. +149,000) : prm f32 (384 floats)
// ---------------------------------------------------------------------------
extern "C" void kernel_launch(void* const* d_in, const int* in_sizes, int n_in,
                              void* d_out, int out_size, void* d_ws, size_t ws_size,
                              hipStream_t stream)
{
  const float* x  = (const float*)d_in[0];
  const float* w1 = (const float*)d_in[1];
  const float* w2 = (const float*)d_in[2];
  const float* g0 = (const float*)d_in[3];
  const float* b0 = (const float*)d_in[4];
  const float* m0 = (const float*)d_in[5];
  const float* v0 = (const float*)d_in[6];
  const float* g1 = (const float*)d_in[7];
  const float* b1 = (const float*)d_in[8];
  const float* m1 = (const float*)d_in[9];
  const float* v1 = (const float*)d_in[10];
  const float* g2 = (const float*)d_in[11];
  const float* b2 = (const float*)d_in[12];
  const float* m2 = (const float*)d_in[13];
  const float* v2 = (const float*)d_in[14];
  const float* a1 = (const float*)d_in[15];
  const float* a2 = (const float*)d_in[16];

  unsigned char* wsb = (unsigned char*)d_ws;
  unsigned short* y1  = (unsigned short*)wsb;
  unsigned short* wt1 = (unsigned short*)(wsb + 102760448);
  unsigned short* wt2 = (unsigned short*)(wsb + 102760448 + 73728);
  float* prm          = (float*)(wsb + 102760448 + 2 * 73728);

  prep_misc<<<16, 256, 0, stream>>>(w1, w2, g0, b0, m0, v0, g1, b1, m1, v1,
                                    g2, b2, m2, v2, wt1, wt2, prm);
  conv1k<<<256, 448, 0, stream>>>(x, wt1, prm, prm + 64, a1, prm + 256, prm + 320, y1);
  conv2k<<<256, 448, 0, stream>>>(y1, wt2, prm + 128, prm + 192, a2, (float*)d_out, x);
}

// Round 20
// 199.209 us; speedup vs baseline: 1.4516x; 1.0451x over previous
//
#include <hip/hip_runtime.h>

#define EPSV 1e-5f

typedef __bf16 bf16x8 __attribute__((ext_vector_type(8)));
typedef float f32x4 __attribute__((ext_vector_type(4)));
typedef unsigned int u32x4 __attribute__((ext_vector_type(4)));
typedef unsigned short u16x4 __attribute__((ext_vector_type(4)));

__device__ __forceinline__ unsigned short f2bf(float f) {
  return __builtin_bit_cast(unsigned short, static_cast<__bf16>(f));
}

// conv1 patch swizzle (R17)
__device__ __forceinline__ int swzB(int P, int k) {
  return P * 128 + (((k ^ (P & 7) ^ ((P >> 2) & 7)) & 7) << 4);
}

constexpr int Himg = 112, Wimg = 112, HWp = Himg * Wimg;  // 12544

// ---------------------------------------------------------------------------
// prep_misc: pack weights + BN scale/shift for all three BNs.
//   prm: [0)=s1 [64)=h1 [128)=s2 [192)=h2 [256)=s0 [320)=h0
// ---------------------------------------------------------------------------
__global__ __launch_bounds__(256) void prep_misc(
    const float* __restrict__ w1, const float* __restrict__ w2,
    const float* __restrict__ g0, const float* __restrict__ b0,
    const float* __restrict__ m0, const float* __restrict__ v0,
    const float* __restrict__ g1, const float* __restrict__ b1,
    const float* __restrict__ m1, const float* __restrict__ v1,
    const float* __restrict__ g2, const float* __restrict__ b2,
    const float* __restrict__ m2, const float* __restrict__ v2,
    unsigned short* __restrict__ wt1, unsigned short* __restrict__ wt2,
    float* __restrict__ prm)
{
  int id = blockIdx.x * 256 + threadIdx.x;
  for (int i = id; i < 9 * 2 * 4 * 512; i += gridDim.x * 256) {
    int j   = i & 7;
    int l   = (i >> 3) & 63;
    int c   = (i >> 9) & 3;
    int ks  = (i >> 11) & 1;
    int tap = i >> 12;
    int co  = c * 16 + (l & 15);
    int ci  = ks * 32 + (l >> 4) * 8 + j;
    int kh  = tap / 3, kw = tap - kh * 3;
    int src = ((co * 64 + ci) * 3 + kh) * 3 + kw;
    wt1[i] = f2bf(w1[src]);
    wt2[i] = f2bf(w2[src]);
  }
  if (id < 64) {
    float s1 = g1[id] * rsqrtf(v1[id] + EPSV);
    prm[id]      = s1;
    prm[64 + id] = b1[id] - m1[id] * s1;
    float s2 = g2[id] * rsqrtf(v2[id] + EPSV);
    prm[128 + id] = s2;
    prm[192 + id] = b2[id] - m2[id] * s2;
    float s0 = g0[id] * rsqrtf(v0[id] + EPSV);
    prm[256 + id] = s0;
    prm[320 + id] = b0[id] - m0[id] * s0;
  }
}

// ---------------------------------------------------------------------------
// conv1k: 2-row tiles, 6-slot ring, one barrier/tile, PREFETCH DISTANCE 2.
//   Loads for the emit at end of tile T+1 (rows r0+5, r0+6) are issued at the
//   START of tile T — ~2 tile-periods of latency slack instead of one K-loop
//   (R19 analysis: 115KB/tile needs 4.7us at fair-share BW > the 2.5us K-loop
//   window -> emit stalled on vmcnt). Ping-pong preg sets, +16 VGPR.
// ---------------------------------------------------------------------------
__global__ __launch_bounds__(448, 2) void conv1k(
    const float* __restrict__ xsrc,
    const unsigned short* __restrict__ wP,
    const float* __restrict__ scale, const float* __restrict__ shift,
    const float* __restrict__ aP,
    const float* __restrict__ bn0sc, const float* __restrict__ bn0sh,
    unsigned short* __restrict__ dstb)
{
  constexpr int RS   = 114 * 128;   // 14592
  constexpr int WOFF = 6 * RS;      // 87552
  __shared__ __align__(16) unsigned char lds[WOFF + 73728];  // 161280

  const int t = threadIdx.x;
  const int b = blockIdx.x;
  const int n = b >> 2, q = b & 3;
  const int qbase = q * 28;
  const size_t ibase = (size_t)n * HWp;
  const float* xn = xsrc + (size_t)n * 64 * HWp;

  const int wv = t >> 6, l = t & 63;
  const int lo = l & 15, grp = l >> 4;

  const int cs = t / 28, wb = t - cs * 28;
  const int w0s = wb * 4;
  float scv[4], shv[4];
#pragma unroll
  for (int cc = 0; cc < 4; ++cc) {
    scv[cc] = bn0sc[cs * 4 + cc];
    shv[cc] = bn0sh[cs * 4 + cc];
  }

  auto load_rowx = [&](int hh, f32x4 (&A)[2], f32x4 (&B)[2]) -> bool {
    bool valid = (unsigned)hh < 112u;
#pragma unroll
    for (int u = 0; u < 2; ++u) {
      f32x4 z = {0.f, 0.f, 0.f, 0.f};
      A[u] = z; B[u] = z;
      if (valid) {
        const int ca = cs * 4 + u * 2;
        A[u] = *reinterpret_cast<const f32x4*>(xn + (size_t)ca * HWp + hh * Wimg + w0s);
        B[u] = *reinterpret_cast<const f32x4*>(xn + (size_t)(ca + 1) * HWp + hh * Wimg + w0s);
      }
    }
    return valid;
  };
  auto emit_rowx = [&](int rbX, const f32x4 (&A)[2], const f32x4 (&B)[2], bool valid) {
#pragma unroll
    for (int u = 0; u < 2; ++u) {
      const int ca = cs * 4 + u * 2;
      const int kk = ca >> 3;
      const int off = (ca & 7) * 2;
#pragma unroll
      for (int j = 0; j < 4; ++j) {
        float fa = valid ? A[u][j] * scv[u * 2] + shv[u * 2] : 0.f;
        float fb = valid ? B[u][j] * scv[u * 2 + 1] + shv[u * 2 + 1] : 0.f;
        unsigned int pk = (unsigned int)f2bf(fa) | ((unsigned int)f2bf(fb) << 16);
        int P = w0s + j + 1;
        *reinterpret_cast<unsigned int*>(&lds[rbX + swzB(P, kk) + off]) = pk;
      }
    }
  };

  // weights full (once), linear region
#pragma unroll
  for (int it = 0; it < 11; ++it) {
    int idx = t + it * 448;
    if (it < 10 || idx < 4608) {
      u32x4 v = *reinterpret_cast<const u32x4*>(wP + idx * 8);
      *reinterpret_cast<u32x4*>(&lds[WOFF + idx * 16]) = v;
    }
  }
  // halo zero: wpad cols (P=0,113), 6 slots
  if (t < 96) {
    int r = t >> 4, P = ((t >> 3) & 1) ? 113 : 0, k = t & 7;
    u32x4 z = {0u, 0u, 0u, 0u};
    *reinterpret_cast<u32x4*>(&lds[r * RS + swzB(P, k)]) = z;
  }
  // rows qbase-1 .. qbase+2 -> slots 0..3
#pragma unroll
  for (int r = 0; r < 4; ++r) {
    f32x4 A[2], B[2];
    bool v = load_rowx(qbase - 1 + r, A, B);
    emit_rowx(r * RS, A, B, v);
  }
  // pregA: rows qbase+3, qbase+4 (emit at end of T=0)
  f32x4 pAa[2][2], pBa[2][2];
  bool pva[2];
#pragma unroll
  for (int rr = 0; rr < 2; ++rr)
    pva[rr] = load_rowx(qbase + 3 + rr, pAa[rr], pBa[rr]);
  __syncthreads();

  int rb0 = 0 * RS, rb1 = 1 * RS, rb2 = 2 * RS, rb3 = 3 * RS, rb4 = 4 * RS, rb5 = 5 * RS;

  for (int T = 0; T < 14; ++T) {
    const int r0 = qbase + T * 2;

    // issue pregB = rows r0+5, r0+6 (emit at end of T+1)
    f32x4 pAb[2][2], pBb[2][2];
    bool pvb[2];
    if (T < 12) {
#pragma unroll
      for (int rr = 0; rr < 2; ++rr)
        pvb[rr] = load_rowx(r0 + 5 + rr, pAb[rr], pBb[rr]);
    }
    __builtin_amdgcn_sched_barrier(0);

    f32x4 acc[4][2];
#pragma unroll
    for (int c = 0; c < 4; ++c)
#pragma unroll
      for (int p = 0; p < 2; ++p) {
        f32x4 z = {0.f, 0.f, 0.f, 0.f};
        acc[c][p] = z;
      }

    // K-loop: 18 steps, reads slots 0..3 only
#pragma unroll
    for (int s = 0; s < 18; ++s) {
      const int tap = s >> 1, ks = s & 1;
      const int dh = tap / 3, dw = tap - dh * 3;
      bf16x8 wf[4], pf[2];
#pragma unroll
      for (int c = 0; c < 4; ++c)
        wf[c] = *reinterpret_cast<const bf16x8*>(&lds[WOFF + (s * 4 + c) * 1024 + l * 16]);
      const int Pr = wv * 16 + lo + dw;
      const int c8 = (ks << 2) | grp;
      const int pbyte = swzB(Pr, c8);
#pragma unroll
      for (int p = 0; p < 2; ++p) {
        const int rr = p + dh;             // 0..3
        const int rbr = (rr == 0) ? rb0 : (rr == 1) ? rb1 : (rr == 2) ? rb2 : rb3;
        pf[p] = *reinterpret_cast<const bf16x8*>(&lds[rbr + pbyte]);
      }
#pragma unroll
      for (int c = 0; c < 4; ++c)
#pragma unroll
        for (int p = 0; p < 2; ++p)
          acc[c][p] = __builtin_amdgcn_mfma_f32_16x16x32_bf16(wf[c], pf[p], acc[c][p], 0, 0, 0);
    }

    // epilogue: rows r0, r0+1 -> y1 bf16 NHWC
#pragma unroll
    for (int c = 0; c < 4; ++c) {
      const int co0 = c * 16 + grp * 4;
      float s_[4], h_[4], a_[4];
#pragma unroll
      for (int j = 0; j < 4; ++j) {
        s_[j] = scale[co0 + j];
        h_[j] = shift[co0 + j];
        a_[j] = aP[co0 + j];
      }
      const int w = wv * 16 + lo;
#pragma unroll
      for (int p = 0; p < 2; ++p) {
        const int hh = r0 + p;
        f32x4 v = acc[c][p];
        u16x4 u;
#pragma unroll
        for (int j = 0; j < 4; ++j) {
          float vv = v[j] * s_[j] + h_[j];
          vv = vv >= 0.f ? vv : vv * a_[j];
          u[j] = f2bf(vv);
        }
        *reinterpret_cast<u16x4*>(dstb + (ibase + hh * Wimg + w) * 64 + co0) = u;
      }
    }

    // emit pregA (rows r0+3, r0+4) to spare slots 4,5 + ONE barrier
    if (T < 13) {
      emit_rowx(rb4, pAa[0], pBa[0], pva[0]);
      emit_rowx(rb5, pAa[1], pBa[1], pva[1]);
      __syncthreads();
    }

    // ping-pong preg sets
    if (T < 12) {
#pragma unroll
      for (int rr = 0; rr < 2; ++rr) {
        pva[rr] = pvb[rr];
#pragma unroll
        for (int u = 0; u < 2; ++u) {
          pAa[rr][u] = pAb[rr][u];
          pBa[rr][u] = pBb[rr][u];
        }
      }
    }

    // rotate by 2: new(0..5) = old(2,3,4,5,0,1)
    int n0 = rb2, n1 = rb3, n2 = rb4, n3 = rb5, n4 = rb0, n5 = rb1;
    rb0 = n0; rb1 = n1; rb2 = n2; rb3 = n3; rb4 = n4; rb5 = n5;
  }
}

// ---------------------------------------------------------------------------
// conv2k: 2-row tiles, 6-slot ring, one barrier/tile, full resid prefetch,
//   PREFETCH DISTANCE 2 on the y1 staging loads (ping-pong preg, +16 VGPR).
// ---------------------------------------------------------------------------
__global__ __launch_bounds__(448, 2) void conv2k(
    const unsigned short* __restrict__ src,   // y1 bf16 NHWC
    const unsigned short* __restrict__ wP,
    const float* __restrict__ scale, const float* __restrict__ shift,
    const float* __restrict__ aP,
    float* __restrict__ dstf,
    const float* __restrict__ resid)
{
  constexpr int RS   = 114 * 128;   // 14592
  constexpr int WOFF = 6 * RS;      // 87552
  __shared__ __align__(16) unsigned char lds[WOFF + 73728];  // 161280

  const int t = threadIdx.x;
  const int b = blockIdx.x;
  const int n = b >> 2, q = b & 3;
  const int qbase = q * 28;
  const size_t ibase = (size_t)n * HWp;

  const int wv = t >> 6, l = t & 63;
  const int lo = l & 15, grp = l >> 4;

  // staging coords (u32x4 chunk-owner map)
  const int wS = t >> 3, kSt = t & 7;

  auto load_y1row2 = [&](int hbase, u32x4 (&pr)[4]) {
#pragma unroll
    for (int it = 0; it < 4; ++it) {
      int j = it >> 1;
      int rem = t + (it & 1) * 448;
      int w = rem >> 3, k = rem & 7;
      int hh = hbase + j;
      u32x4 val = {0u, 0u, 0u, 0u};
      if ((unsigned)hh < 112u)
        val = *reinterpret_cast<const u32x4*>(src + (ibase + hh * Wimg + w) * 64 + k * 8);
      pr[it] = val;
    }
  };

#pragma unroll
  for (int it = 0; it < 11; ++it) {
    int idx = t + it * 448;
    if (it < 10 || idx < 4608) {
      u32x4 v = *reinterpret_cast<const u32x4*>(wP + idx * 8);
      *reinterpret_cast<u32x4*>(&lds[WOFF + idx * 16]) = v;
    }
  }
  // halo zero: 6 slots
  if (t < 96) {
    int r = t >> 4, P = ((t >> 3) & 1) ? 113 : 0, k = t & 7;
    u32x4 z = {0u, 0u, 0u, 0u};
    *reinterpret_cast<u32x4*>(&lds[r * RS + P * 128 + ((k ^ (P & 7)) << 4)]) = z;
  }
  // rows qbase-1 .. qbase+2 -> slots 0..3
#pragma unroll
  for (int it = 0; it < 8; ++it) {
    int r = it >> 1;
    int rem = t + (it & 1) * 448;
    int w = rem >> 3, k = rem & 7;
    int hh = qbase - 1 + r;
    u32x4 val = {0u, 0u, 0u, 0u};
    if ((unsigned)hh < 112u)
      val = *reinterpret_cast<const u32x4*>(src + (ibase + hh * Wimg + w) * 64 + k * 8);
    int P = w + 1;
    *reinterpret_cast<u32x4*>(&lds[r * RS + P * 128 + ((k ^ (P & 7)) << 4)]) = val;
  }
  // pregA: rows qbase+3, qbase+4
  u32x4 prgA[4];
  load_y1row2(qbase + 3, prgA);
  __syncthreads();

  int rb0 = 0 * RS, rb1 = 1 * RS, rb2 = 2 * RS, rb3 = 3 * RS, rb4 = 4 * RS, rb5 = 5 * RS;

  for (int T = 0; T < 14; ++T) {
    const int r0 = qbase + T * 2;

    // FULL resid prefetch (32 f32): drains under the K-loop
    float rres[4][2][4];
#pragma unroll
    for (int c = 0; c < 4; ++c)
#pragma unroll
      for (int p = 0; p < 2; ++p)
#pragma unroll
        for (int j = 0; j < 4; ++j) {
          size_t idx = ((size_t)(n * 64 + c * 16 + grp * 4 + j) * Himg + (r0 + p)) * Wimg
                       + wv * 16 + lo;
          rres[c][p][j] = resid[idx];
        }

    // issue pregB = rows r0+5, r0+6 (emit at end of T+1)
    u32x4 prgB[4];
    if (T < 12) load_y1row2(r0 + 5, prgB);
    __builtin_amdgcn_sched_barrier(0);

    f32x4 acc[4][2];
#pragma unroll
    for (int c = 0; c < 4; ++c)
#pragma unroll
      for (int p = 0; p < 2; ++p) {
        f32x4 z = {0.f, 0.f, 0.f, 0.f};
        acc[c][p] = z;
      }

#pragma unroll
    for (int s = 0; s < 18; ++s) {
      const int tap = s >> 1, ks = s & 1;
      const int dh = tap / 3, dw = tap - dh * 3;
      bf16x8 wf[4], pf[2];
#pragma unroll
      for (int c = 0; c < 4; ++c)
        wf[c] = *reinterpret_cast<const bf16x8*>(&lds[WOFF + (s * 4 + c) * 1024 + l * 16]);
      const int Pr = wv * 16 + lo + dw;
      const int c8 = (ks << 2) | grp;
      const int pbyte = Pr * 128 + ((c8 ^ (Pr & 7)) << 4);
#pragma unroll
      for (int p = 0; p < 2; ++p) {
        const int rr = p + dh;
        const int rbr = (rr == 0) ? rb0 : (rr == 1) ? rb1 : (rr == 2) ? rb2 : rb3;
        pf[p] = *reinterpret_cast<const bf16x8*>(&lds[rbr + pbyte]);
      }
#pragma unroll
      for (int c = 0; c < 4; ++c)
#pragma unroll
        for (int p = 0; p < 2; ++p)
          acc[c][p] = __builtin_amdgcn_mfma_f32_16x16x32_bf16(wf[c], pf[p], acc[c][p], 0, 0, 0);
    }

#pragma unroll
    for (int c = 0; c < 4; ++c) {
      const int co0 = c * 16 + grp * 4;
      float s_[4], h_[4], a_[4];
#pragma unroll
      for (int j = 0; j < 4; ++j) {
        s_[j] = scale[co0 + j];
        h_[j] = shift[co0 + j];
        a_[j] = aP[co0 + j];
      }
      const int w = wv * 16 + lo;
#pragma unroll
      for (int p = 0; p < 2; ++p) {
        const int hh = r0 + p;
        f32x4 v = acc[c][p];
#pragma unroll
        for (int j = 0; j < 4; ++j) {
          size_t idx = ((size_t)(n * 64 + co0 + j) * Himg + hh) * Wimg + w;
          float vv = v[j] * s_[j] + h_[j] + rres[c][p][j];
          vv = vv >= 0.f ? vv : vv * a_[j];
          dstf[idx] = vv;
        }
      }
    }

    // emit pregA (rows r0+3, r0+4) to spare slots 4,5 + ONE barrier
    if (T < 13) {
#pragma unroll
      for (int it = 0; it < 4; ++it) {
        int j = it >> 1;
        int rem = t + (it & 1) * 448;
        int w = rem >> 3, k = rem & 7;
        int P = w + 1;
        const int dst = (j == 0) ? rb4 : rb5;
        *reinterpret_cast<u32x4*>(&lds[dst + P * 128 + ((k ^ (P & 7)) << 4)]) = prgA[it];
      }
      __syncthreads();
    }

    // ping-pong preg sets
    if (T < 12) {
#pragma unroll
      for (int it = 0; it < 4; ++it) prgA[it] = prgB[it];
    }

    // rotate by 2: new(0..5) = old(2,3,4,5,0,1)
    int n0 = rb2, n1 = rb3, n2 = rb4, n3 = rb5, n4 = rb0, n5 = rb1;
    rb0 = n0; rb1 = n1; rb2 = n2; rb3 = n3; rb4 = n4; rb5 = n5;
  }
}

// ---------------------------------------------------------------------------
// scratch map:
//   d_ws [0 .. 102,760,448)     : y1 bf16 NHWC
//   d_ws [+0 .. +73,728)        : wt1 packed bf16
//   d_ws [+73,728 .. +147,456)  : wt2 packed bf16
//   d_ws [+147,456 .. +149,000) : prm f32 (384 floats)
// ---------------------------------------------------------------------------
extern "C" void kernel_launch(void* const* d_in, const int* in_sizes, int n_in,
                              void* d_out, int out_size, void* d_ws, size_t ws_size,
                              hipStream_t stream)
{
  const float* x  = (const float*)d_in[0];
  const float* w1 = (const float*)d_in[1];
  const float* w2 = (const float*)d_in[2];
  const float* g0 = (const float*)d_in[3];
  const float* b0 = (const float*)d_in[4];
  const float* m0 = (const float*)d_in[5];
  const float* v0 = (const float*)d_in[6];
  const float* g1 = (const float*)d_in[7];
  const float* b1 = (const float*)d_in[8];
  const float* m1 = (const float*)d_in[9];
  const float* v1 = (const float*)d_in[10];
  const float* g2 = (const float*)d_in[11];
  const float* b2 = (const float*)d_in[12];
  const float* m2 = (const float*)d_in[13];
  const float* v2 = (const float*)d_in[14];
  const float* a1 = (const float*)d_in[15];
  const float* a2 = (const float*)d_in[16];

  unsigned char* wsb = (unsigned char*)d_ws;
  unsigned short* y1  = (unsigned short*)wsb;
  unsigned short* wt1 = (unsigned short*)(wsb + 102760448);
  unsigned short* wt2 = (unsigned short*)(wsb + 102760448 + 73728);
  float* prm          = (float*)(wsb + 102760448 + 2 * 73728);

  prep_misc<<<16, 256, 0, stream>>>(w1, w2, g0, b0, m0, v0, g1, b1, m1, v1,
                                    g2, b2, m2, v2, wt1, wt2, prm);
  conv1k<<<256, 448, 0, stream>>>(x, wt1, prm, prm + 64, a1, prm + 256, prm + 320, y1);
  conv2k<<<256, 448, 0, stream>>>(y1, wt2, prm + 128, prm + 192, a2, (float*)d_out, x);
}